// Round 7
// baseline (936.868 us; speedup 1.0000x reference)
//
#include <hip/hip_runtime.h>

// Problem dims (fixed by the reference)
#define T_TOK 2048      // B*S tokens
#define H_DIM 2048
#define E_NUM 32
#define I_DIM 1024
#define IS_DIM 2048
#define SLOT_CAP 2048
#define NE_ALL 34        // 32 routed + 2 shared pseudo-experts
#define GU_TILES 192     // <=160 routed + 32 shared
#define DN_TILES 176     // <=160 routed + 16 shared (K=2048)
#define ACT_SLOTS 24576  // sum pad128(cnt_e) (<=20448) + 4096 shared

typedef __bf16 bf16x8 __attribute__((ext_vector_type(8)));
typedef float  f32x4  __attribute__((ext_vector_type(4)));
static_assert(sizeof(bf16x8) == 16, "bf16x8 must be 16B");

// Workspace layout (bytes). Total ~59 MB (weights consumed fp32 in-place).
#define OFF_CNT   ((size_t)0)            // cnt[34] int
#define OFF_NTGU  ((size_t)192)
#define OFF_NTDN  ((size_t)196)
#define OFF_BASE  ((size_t)256)          // base[34] int
#define OFF_TGU   ((size_t)512)          // tilesGU[192] uint
#define OFF_TDN   ((size_t)1280)         // tilesDN[176] uint
#define OFF_PAIRS ((size_t)2048)         // pairs[34][2048] uint = 278,528
#define OFF_XB    ((size_t)280576)       // xb [T,H] bf16 = 8,388,608
#define OFF_ACT   ((size_t)8669184)      // act [24576][1024] bf16 = 50,331,648

__device__ __forceinline__ unsigned short f2bf(float f) {
  unsigned int u = __float_as_uint(f);
  u += 0x7fffu + ((u >> 16) & 1u);   // round-to-nearest-even
  return (unsigned short)(u >> 16);
}

// packed bf16 convert: low16 = bf16(lo), high16 = bf16(hi)
__device__ __forceinline__ unsigned int cvtpk(float lo, float hi) {
  unsigned int r;
  asm volatile("v_cvt_pk_bf16_f32 %0, %1, %2" : "=v"(r) : "v"(lo), "v"(hi));
  return r;
}

__device__ __forceinline__ void gld16(const void* g, void* l) {
  __builtin_amdgcn_global_load_lds(
      (const __attribute__((address_space(1))) unsigned int*)g,
      (__attribute__((address_space(3))) unsigned int*)l, 16, 0, 0);
}

// ---------------------------------------------------------------------------
// Router: scores = sigmoid(x @ gw^T); top-8; renorm; *2.5 -> pair lists.
// ---------------------------------------------------------------------------
__global__ __launch_bounds__(256) void router_kernel(
    const float* __restrict__ x, const float* __restrict__ gw,
    int* __restrict__ cnt, unsigned int* __restrict__ pairs)
{
  const int t = blockIdx.x;
  __shared__ float xs[H_DIM];
  __shared__ float sc[E_NUM];
  const float4* xr = (const float4*)(x + (long)t * H_DIM);
  for (int i = threadIdx.x; i < H_DIM / 4; i += 256) ((float4*)xs)[i] = xr[i];
  __syncthreads();
  const int e = threadIdx.x >> 3, p = threadIdx.x & 7;
  const float4* ga = (const float4*)(gw + (long)e * H_DIM);
  const float4* xa = (const float4*)xs;
  float s = 0.f;
  #pragma unroll 4
  for (int i = p * 64; i < p * 64 + 64; ++i) {
    float4 a = ga[i], b = xa[i];
    s += a.x * b.x + a.y * b.y + a.z * b.z + a.w * b.w;
  }
  s += __shfl_down(s, 4, 8);
  s += __shfl_down(s, 2, 8);
  s += __shfl_down(s, 1, 8);
  if (p == 0) sc[e] = 1.f / (1.f + expf(-s));
  __syncthreads();
  if (threadIdx.x == 0) {
    float v[E_NUM];
    #pragma unroll
    for (int i = 0; i < E_NUM; ++i) v[i] = sc[i];
    unsigned mask = 0; float sum = 0.f;
    int sel[8]; float wv[8];
    for (int k = 0; k < 8; ++k) {
      float best = -1.f; int bi = 0;
      for (int i = 0; i < E_NUM; ++i)
        if (!((mask >> i) & 1u) && v[i] > best) { best = v[i]; bi = i; }
      mask |= 1u << bi; sel[k] = bi; wv[k] = best; sum += best;
    }
    const float scale = 2.5f / (sum + 1e-20f);
    for (int k = 0; k < 8; ++k) {
      const int slot = atomicAdd(&cnt[sel[k]], 1);
      if (slot < SLOT_CAP) {
        const unsigned int w16 = (unsigned int)f2bf(wv[k] * scale);
        pairs[sel[k] * SLOT_CAP + slot] = (w16 << 16) | (unsigned int)t;
      }
    }
  }
}

// ---------------------------------------------------------------------------
__global__ __launch_bounds__(256) void build_tiles_kernel(
    int* __restrict__ cnt, int* __restrict__ base,
    unsigned int* __restrict__ tgu, int* __restrict__ ntgu,
    unsigned int* __restrict__ tdn, int* __restrict__ ntdn,
    unsigned int* __restrict__ pairs)
{
  const int t = threadIdx.x;
  for (int s = t; s < T_TOK; s += 256) {
    const unsigned int pv = (0x3F80u << 16) | (unsigned int)s;  // w=1.0 bf16
    pairs[32 * SLOT_CAP + s] = pv;
    pairs[33 * SLOT_CAP + s] = pv;
  }
  if (t == 0) {
    cnt[32] = T_TOK; cnt[33] = T_TOK;
    int b = 0, ngu = 0, ndn = 0;
    for (int e = 0; e < NE_ALL; ++e) {
      const int c = (e < 32) ? cnt[e] : T_TOK;
      base[e] = b;
      for (int m0 = 0; m0 < c; m0 += 128) {
        tgu[ngu++] = ((unsigned int)e << 16) | (unsigned int)m0;
        if (e < 33) tdn[ndn++] = ((unsigned int)e << 16) | (unsigned int)m0;
      }
      b += (c + 127) & ~127;
    }
    *ntgu = ngu; *ntdn = ndn;
  }
}

// ---------------------------------------------------------------------------
__global__ __launch_bounds__(256) void cvt_bf16_kernel(
    const float* __restrict__ in, unsigned short* __restrict__ out, int n4)
{
  int i = blockIdx.x * 256 + threadIdx.x;
  if (i >= n4) return;
  float4 v = ((const float4*)in)[i];
  ushort4 o;
  o.x = f2bf(v.x); o.y = f2bf(v.y); o.z = f2bf(v.z); o.w = f2bf(v.w);
  ((ushort4*)out)[i] = o;
}

// ---------------------------------------------------------------------------
// Unified gate+up GEMM over GU tile list. B staged DIRECTLY from fp32 weights
// (global float4 pair -> cvt_pk bf16 -> swizzled ds_write_b32); A via gld16.
// Element (n,k) lives at LDS byte n*128 + ((k>>3)^(n&7))*16 + (k&7)*2 — the
// exact invariant the read side's (ko ^ ksw) expects. 512 thr, tile 128x64,
// BK=64, 2-phase dbuf (T14 issue-early/write-late), 1 barrier/iter.
// ---------------------------------------------------------------------------
__global__ __launch_bounds__(512, 3) void gate_up_moe_kernel(
    const unsigned short* __restrict__ xb,
    const float* __restrict__ wg,
    const float* __restrict__ wu,
    const float* __restrict__ wsg,
    const float* __restrict__ wsu,
    const int* __restrict__ cnt,
    const int* __restrict__ base,
    const unsigned int* __restrict__ pairs,
    const unsigned int* __restrict__ tiles,
    const int* __restrict__ ntp,
    unsigned short* __restrict__ act)
{
  const int ti = blockIdx.y;
  if (ti >= *ntp) return;
  const unsigned int tile = tiles[ti];
  const int e  = (int)(tile >> 16);
  const int m0 = (int)(tile & 0xFFFFu);
  const int cnte = cnt[e];
  const int be = base[e];
  const int n0 = blockIdx.x * 64;
  const float* Bg; const float* Bu; long ldB;
  if (e < 32) {
    Bg = wg + (long)e * H_DIM * I_DIM + n0;
    Bu = wu + (long)e * H_DIM * I_DIM + n0;
    ldB = I_DIM;
  } else {
    Bg = wsg + (e - 32) * I_DIM + n0;
    Bu = wsu + (e - 32) * I_DIM + n0;
    ldB = IS_DIM;
  }

  __shared__ unsigned short sA[2][128 * 64];
  __shared__ unsigned short sBg[2][64 * 64];
  __shared__ unsigned short sBu[2][64 * 64];

  const int tid = threadIdx.x;
  const int lane = tid & 63;
  const int wid = tid >> 6;
  const int wm = wid >> 1, wn = wid & 1;
  const int l15 = lane & 15;
  const int lk  = (lane >> 4) * 8;
  const int srow = tid >> 3;
  const int scol = (tid & 7) * 8;
  const int scolsw = ((tid & 7) ^ (srow & 7)) * 8;
  const int ksw = (l15 & 7) << 3;

  // B staging mapping: thread -> (k-pair, 4-col group)
  const int kA = ((tid & 15) | ((tid >> 8) << 4)) * 2;   // 0,2,..,62
  const int cA = ((tid >> 4) & 15) * 4;                  // 0,4,..,60

  const unsigned short* asrc[2];
  #pragma unroll
  for (int r = 0; r < 2; ++r) {
    const int slot = m0 + r * 64 + srow;
    const unsigned int pr = (slot < cnte) ? pairs[e * SLOT_CAP + slot] : 0u;
    asrc[r] = xb + (long)(pr & 0xFFFFu) * H_DIM + scolsw;
  }

  const f32x4 fz = {0.f, 0.f, 0.f, 0.f};
  f32x4 accg[2][2], accu[2][2];
  #pragma unroll
  for (int i = 0; i < 2; ++i)
    #pragma unroll
    for (int j = 0; j < 2; ++j) { accg[i][j] = fz; accu[i][j] = fz; }

  float4 vg0, vg1, vu0, vu1;

#define LOADB_GU(k0) do {                                                      \
    const float* bg = Bg + (long)((k0) + kA) * ldB + cA;                       \
    const float* bu = Bu + (long)((k0) + kA) * ldB + cA;                       \
    vg0 = *(const float4*)bg; vg1 = *(const float4*)(bg + ldB);                \
    vu0 = *(const float4*)bu; vu1 = *(const float4*)(bu + ldB);                \
  } while (0)

#define WRITEB_GU(buf) do {                                                    \
    _Pragma("unroll")                                                          \
    for (int j = 0; j < 4; ++j) {                                              \
      const int n = cA + j;                                                    \
      const int li = n * 64 + (((kA >> 3) ^ (n & 7)) << 3) + (kA & 7);         \
      *(unsigned int*)&sBg[buf][li] =                                          \
          cvtpk(((const float*)&vg0)[j], ((const float*)&vg1)[j]);             \
      *(unsigned int*)&sBu[buf][li] =                                          \
          cvtpk(((const float*)&vu0)[j], ((const float*)&vu1)[j]);             \
    }                                                                          \
  } while (0)

#define STAGEA_GU(buf, k0) do {                                                \
    gld16(asrc[0] + (k0), sA[buf] + srow * 64 + scol);                         \
    gld16(asrc[1] + (k0), sA[buf] + (64 + srow) * 64 + scol);                  \
  } while (0)

#define COMP_GU(buf) do {                                                      \
    _Pragma("unroll")                                                          \
    for (int kk = 0; kk < 2; ++kk) {                                           \
      const int ko = kk * 32 + lk;                                             \
      bf16x8 a[2], g[2], u[2];                                                 \
      _Pragma("unroll")                                                        \
      for (int mi = 0; mi < 2; ++mi)                                           \
        a[mi] = *(const bf16x8*)(sA[buf] + (wm * 32 + mi * 16 + l15) * 64 +    \
                                 (ko ^ ksw));                                  \
      _Pragma("unroll")                                                        \
      for (int ni = 0; ni < 2; ++ni) {                                         \
        g[ni] = *(const bf16x8*)(sBg[buf] + (wn * 32 + ni * 16 + l15) * 64 +   \
                                 (ko ^ ksw));                                  \
        u[ni] = *(const bf16x8*)(sBu[buf] + (wn * 32 + ni * 16 + l15) * 64 +   \
                                 (ko ^ ksw));                                  \
      }                                                                        \
      _Pragma("unroll")                                                        \
      for (int mi = 0; mi < 2; ++mi)                                           \
        _Pragma("unroll")                                                      \
        for (int ni = 0; ni < 2; ++ni) {                                       \
          accg[mi][ni] = __builtin_amdgcn_mfma_f32_16x16x32_bf16(              \
              a[mi], g[ni], accg[mi][ni], 0, 0, 0);                            \
          accu[mi][ni] = __builtin_amdgcn_mfma_f32_16x16x32_bf16(              \
              a[mi], u[ni], accu[mi][ni], 0, 0, 0);                            \
        }                                                                      \
    }                                                                          \
  } while (0)

  // prologue: stage K-step 0 into buf 0
  LOADB_GU(0);
  STAGEA_GU(0, 0);
  WRITEB_GU(0);
  __syncthreads();
  for (int t = 0; t < 32; ++t) {
    const int cur = t & 1, nxt = cur ^ 1;
    if (t < 31) { LOADB_GU((t + 1) * 64); STAGEA_GU(nxt, (t + 1) * 64); }
    COMP_GU(cur);
    if (t < 31) WRITEB_GU(nxt);
    __syncthreads();
  }
#undef LOADB_GU
#undef WRITEB_GU
#undef STAGEA_GU
#undef COMP_GU

  const int colb = n0 + wn * 32;
  #pragma unroll
  for (int mi = 0; mi < 2; ++mi) {
    #pragma unroll
    for (int r = 0; r < 4; ++r) {
      const int slot = m0 + wm * 32 + mi * 16 + (lane >> 4) * 4 + r;
      if (slot < cnte) {
        const unsigned int pr = pairs[e * SLOT_CAP + slot];
        const float w = __uint_as_float(pr & 0xFFFF0000u);
        #pragma unroll
        for (int ni = 0; ni < 2; ++ni) {
          const float gv = accg[mi][ni][r];
          const float uv = accu[mi][ni][r];
          const float sv = (gv / (1.f + expf(-gv))) * uv * w;
          act[((long)(be + slot)) * I_DIM + colb + ni * 16 + l15] = f2bf(sv);
        }
      }
    }
  }
}

// ---------------------------------------------------------------------------
// Unified down GEMM over DN tile list. B staged directly from fp32 wd/wsd
// ([K][N] orientation, ldB = H_DIM for both). e=32 runs K=2048 (A spans both
// shared act panels). atomicAdd-scatter onto zeroed out.
// ---------------------------------------------------------------------------
__global__ __launch_bounds__(512, 3) void down_moe_kernel(
    const unsigned short* __restrict__ act,
    const float* __restrict__ wd,
    const float* __restrict__ wsd,
    const int* __restrict__ cnt,
    const int* __restrict__ base,
    const unsigned int* __restrict__ pairs,
    const unsigned int* __restrict__ tiles,
    const int* __restrict__ ntp,
    float* __restrict__ out)
{
  const int ti = blockIdx.y;
  if (ti >= *ntp) return;
  const unsigned int tile = tiles[ti];
  const int e  = (int)(tile >> 16);
  const int m0 = (int)(tile & 0xFFFFu);
  const int cnte = cnt[e];
  const int n0 = blockIdx.x * 64;
  const unsigned short* A = act + ((long)base[e] + m0) * I_DIM;
  const float* B = (e < 32) ? wd + (long)e * I_DIM * H_DIM + n0 : wsd + n0;
  const int nk = (e == 32) ? 32 : 16;   // K-steps of 64

  __shared__ unsigned short sA[2][128 * 64];
  __shared__ unsigned short sB[2][64 * 64];

  const int tid = threadIdx.x;
  const int lane = tid & 63;
  const int wid = tid >> 6;
  const int wm = wid >> 1, wn = wid & 1;
  const int l15 = lane & 15;
  const int lk  = (lane >> 4) * 8;
  const int srow = tid >> 3;
  const int scol = (tid & 7) * 8;
  const int scolsw = ((tid & 7) ^ (srow & 7)) * 8;
  const int ksw = (l15 & 7) << 3;

  const int kA = ((tid & 15) | ((tid >> 8) << 4)) * 2;   // 0,2,..,62
  const int cA = ((tid >> 4) & 15) * 4;                  // 0,4,..,60

  const f32x4 fz = {0.f, 0.f, 0.f, 0.f};
  f32x4 acc[2][2];
  #pragma unroll
  for (int i = 0; i < 2; ++i)
    #pragma unroll
    for (int j = 0; j < 2; ++j) acc[i][j] = fz;

  float4 vb0, vb1;

#define LOADB_DN(k0) do {                                                      \
    const float* bp = B + (long)((k0) + kA) * H_DIM + cA;                      \
    vb0 = *(const float4*)bp; vb1 = *(const float4*)(bp + H_DIM);              \
  } while (0)

#define WRITEB_DN(buf) do {                                                    \
    _Pragma("unroll")                                                          \
    for (int j = 0; j < 4; ++j) {                                              \
      const int n = cA + j;                                                    \
      const int li = n * 64 + (((kA >> 3) ^ (n & 7)) << 3) + (kA & 7);         \
      *(unsigned int*)&sB[buf][li] =                                           \
          cvtpk(((const float*)&vb0)[j], ((const float*)&vb1)[j]);             \
    }                                                                          \
  } while (0)

#define STAGEA_DN(buf, k0) do {                                                \
    const long koff = (long)((k0) & 1023) +                                    \
                      (long)((k0) >> 10) * (2048L * 1024L);                    \
    gld16(A + (long)srow * I_DIM + koff + scolsw,                              \
          sA[buf] + srow * 64 + scol);                                         \
    gld16(A + (long)(64 + srow) * I_DIM + koff + scolsw,                       \
          sA[buf] + (64 + srow) * 64 + scol);                                  \
  } while (0)

#define COMP_DN(buf) do {                                                      \
    _Pragma("unroll")                                                          \
    for (int kk = 0; kk < 2; ++kk) {                                           \
      const int ko = kk * 32 + lk;                                             \
      bf16x8 a[2], b[2];                                                       \
      _Pragma("unroll")                                                        \
      for (int mi = 0; mi < 2; ++mi)                                           \
        a[mi] = *(const bf16x8*)(sA[buf] + (wm * 32 + mi * 16 + l15) * 64 +    \
                                 (ko ^ ksw));                                  \
      _Pragma("unroll")                                                        \
      for (int ni = 0; ni < 2; ++ni)                                           \
        b[ni] = *(const bf16x8*)(sB[buf] + (wn * 32 + ni * 16 + l15) * 64 +    \
                                 (ko ^ ksw));                                  \
      _Pragma("unroll")                                                        \
      for (int mi = 0; mi < 2; ++mi)                                           \
        _Pragma("unroll")                                                      \
        for (int ni = 0; ni < 2; ++ni)                                         \
          acc[mi][ni] = __builtin_amdgcn_mfma_f32_16x16x32_bf16(               \
              a[mi], b[ni], acc[mi][ni], 0, 0, 0);                             \
    }                                                                          \
  } while (0)

  LOADB_DN(0);
  STAGEA_DN(0, 0);
  WRITEB_DN(0);
  __syncthreads();
  for (int t = 0; t < nk; ++t) {
    const int cur = t & 1, nxt = cur ^ 1;
    if (t < nk - 1) { LOADB_DN((t + 1) * 64); STAGEA_DN(nxt, (t + 1) * 64); }
    COMP_DN(cur);
    if (t < nk - 1) WRITEB_DN(nxt);
    __syncthreads();
  }
#undef LOADB_DN
#undef WRITEB_DN
#undef STAGEA_DN
#undef COMP_DN

  #pragma unroll
  for (int mi = 0; mi < 2; ++mi) {
    #pragma unroll
    for (int r = 0; r < 4; ++r) {
      const int slot = m0 + wm * 32 + mi * 16 + (lane >> 4) * 4 + r;
      if (slot < cnte) {
        const int tok = (int)(pairs[e * SLOT_CAP + slot] & 0xFFFFu);
        #pragma unroll
        for (int ni = 0; ni < 2; ++ni)
          atomicAdd(out + (long)tok * H_DIM + n0 + wn * 32 + ni * 16 + l15,
                    acc[mi][ni][r]);
      }
    }
  }
}

// ---------------------------------------------------------------------------
extern "C" void kernel_launch(void* const* d_in, const int* in_sizes, int n_in,
                              void* d_out, int out_size, void* d_ws, size_t ws_size,
                              hipStream_t stream) {
  (void)in_sizes; (void)n_in; (void)ws_size;
  const float* x   = (const float*)d_in[0];
  const float* gw  = (const float*)d_in[1];
  const float* wg  = (const float*)d_in[2];
  const float* wu  = (const float*)d_in[3];
  const float* wd  = (const float*)d_in[4];
  const float* wsg = (const float*)d_in[5];
  const float* wsu = (const float*)d_in[6];
  const float* wsd = (const float*)d_in[7];
  float* out = (float*)d_out;
  char* ws = (char*)d_ws;

  int*            cnt   = (int*)(ws + OFF_CNT);
  int*            ntgu  = (int*)(ws + OFF_NTGU);
  int*            ntdn  = (int*)(ws + OFF_NTDN);
  int*            basep = (int*)(ws + OFF_BASE);
  unsigned int*   tgu   = (unsigned int*)(ws + OFF_TGU);
  unsigned int*   tdn   = (unsigned int*)(ws + OFF_TDN);
  unsigned int*   pairs = (unsigned int*)(ws + OFF_PAIRS);
  unsigned short* xb    = (unsigned short*)(ws + OFF_XB);
  unsigned short* actb  = (unsigned short*)(ws + OFF_ACT);

  hipMemsetAsync(ws + OFF_CNT, 0, 256, stream);           // cnt + nt
  hipMemsetAsync(out, 0, (size_t)out_size * sizeof(float), stream);

  router_kernel<<<T_TOK, 256, 0, stream>>>(x, gw, cnt, pairs);
  build_tiles_kernel<<<1, 256, 0, stream>>>(cnt, basep, tgu, ntgu, tdn, ntdn,
                                            pairs);
  cvt_bf16_kernel<<<(T_TOK * H_DIM / 4 + 255) / 256, 256, 0, stream>>>(
      x, xb, T_TOK * H_DIM / 4);

  // unified gate+up (routed + shared pseudo-experts), fp32 weights staged
  // in-kernel -> compact act (router weights folded in)
  gate_up_moe_kernel<<<dim3(16, GU_TILES), 512, 0, stream>>>(
      xb, wg, wu, wsg, wsu, cnt, basep, pairs, tgu, ntgu, actb);

  // unified down (routed K=1024, shared K=2048), fp32 weights staged
  // in-kernel -> atomicAdd onto zeroed out
  down_moe_kernel<<<dim3(32, DN_TILES), 512, 0, stream>>>(
      actb, wd, wsd, cnt, basep, pairs, tdn, ntdn, out);
}

// Round 8
// 845.237 us; speedup vs baseline: 1.1084x; 1.1084x over previous
//
#include <hip/hip_runtime.h>

// Problem dims (fixed by the reference)
#define T_TOK 2048      // B*S tokens
#define H_DIM 2048
#define E_NUM 32
#define I_DIM 1024
#define IS_DIM 2048
#define K_TOT (E_NUM * I_DIM + IS_DIM)   // 34816
#define SLOT_CAP 2048
#define NE_ALL 34        // 32 routed + 2 shared pseudo-experts
#define GU_TILES 192     // <=160 routed + 32 shared
#define DN_TILES 176     // <=160 routed + 16 shared (K=2048)
#define ACT_SLOTS 24576  // sum pad128(cnt_e) (<=20448) + 4096 shared

typedef __bf16 bf16x8 __attribute__((ext_vector_type(8)));
typedef float  f32x4  __attribute__((ext_vector_type(4)));
static_assert(sizeof(bf16x8) == 16, "bf16x8 must be 16B");

// Workspace layout (bytes). Total = 486,819,840.
#define OFF_CNT   ((size_t)0)            // cnt[34] int
#define OFF_NTGU  ((size_t)192)
#define OFF_NTDN  ((size_t)196)
#define OFF_BASE  ((size_t)256)          // base[34] int
#define OFF_TGU   ((size_t)512)          // tilesGU[192] uint
#define OFF_TDN   ((size_t)1280)         // tilesDN[176] uint
#define OFF_PAIRS ((size_t)2048)         // pairs[34][2048] uint = 278,528
#define OFF_XB    ((size_t)280576)       // xb [T,H] bf16 = 8,388,608
#define OFF_WGT   ((size_t)8669184)      // wgT [E][I][H] bf16
#define OFF_WUT   ((size_t)142886912)    // wuT [E][I][H] bf16
#define OFF_WSGT  ((size_t)277104640)    // wsgT [IS][H] bf16
#define OFF_WSUT  ((size_t)285493248)    // wsuT [IS][H] bf16
#define OFF_WDT   ((size_t)293881856)    // wdT [H][K_TOT] bf16
#define OFF_ACT   ((size_t)436488192)    // act [24576][1024] bf16 = 50,331,648

__device__ __forceinline__ unsigned short f2bf(float f) {
  unsigned int u = __float_as_uint(f);
  u += 0x7fffu + ((u >> 16) & 1u);   // round-to-nearest-even
  return (unsigned short)(u >> 16);
}

__device__ __forceinline__ void gld16(const void* g, void* l) {
  __builtin_amdgcn_global_load_lds(
      (const __attribute__((address_space(1))) unsigned int*)g,
      (__attribute__((address_space(3))) unsigned int*)l, 16, 0, 0);
}

// ---------------------------------------------------------------------------
// Router: scores = sigmoid(x @ gw^T); top-8; renorm; *2.5 -> pair lists.
// ---------------------------------------------------------------------------
__global__ __launch_bounds__(256) void router_kernel(
    const float* __restrict__ x, const float* __restrict__ gw,
    int* __restrict__ cnt, unsigned int* __restrict__ pairs)
{
  const int t = blockIdx.x;
  __shared__ float xs[H_DIM];
  __shared__ float sc[E_NUM];
  const float4* xr = (const float4*)(x + (long)t * H_DIM);
  for (int i = threadIdx.x; i < H_DIM / 4; i += 256) ((float4*)xs)[i] = xr[i];
  __syncthreads();
  const int e = threadIdx.x >> 3, p = threadIdx.x & 7;
  const float4* ga = (const float4*)(gw + (long)e * H_DIM);
  const float4* xa = (const float4*)xs;
  float s = 0.f;
  #pragma unroll 4
  for (int i = p * 64; i < p * 64 + 64; ++i) {
    float4 a = ga[i], b = xa[i];
    s += a.x * b.x + a.y * b.y + a.z * b.z + a.w * b.w;
  }
  s += __shfl_down(s, 4, 8);
  s += __shfl_down(s, 2, 8);
  s += __shfl_down(s, 1, 8);
  if (p == 0) sc[e] = 1.f / (1.f + expf(-s));
  __syncthreads();
  if (threadIdx.x == 0) {
    float v[E_NUM];
    #pragma unroll
    for (int i = 0; i < E_NUM; ++i) v[i] = sc[i];
    unsigned mask = 0; float sum = 0.f;
    int sel[8]; float wv[8];
    for (int k = 0; k < 8; ++k) {
      float best = -1.f; int bi = 0;
      for (int i = 0; i < E_NUM; ++i)
        if (!((mask >> i) & 1u) && v[i] > best) { best = v[i]; bi = i; }
      mask |= 1u << bi; sel[k] = bi; wv[k] = best; sum += best;
    }
    const float scale = 2.5f / (sum + 1e-20f);
    for (int k = 0; k < 8; ++k) {
      const int slot = atomicAdd(&cnt[sel[k]], 1);
      if (slot < SLOT_CAP) {
        const unsigned int w16 = (unsigned int)f2bf(wv[k] * scale);
        pairs[sel[k] * SLOT_CAP + slot] = (w16 << 16) | (unsigned int)t;
      }
    }
  }
}

// ---------------------------------------------------------------------------
// Build tile lists + per-expert act bases; fill shared pseudo-expert pairs.
// ---------------------------------------------------------------------------
__global__ __launch_bounds__(256) void build_tiles_kernel(
    int* __restrict__ cnt, int* __restrict__ base,
    unsigned int* __restrict__ tgu, int* __restrict__ ntgu,
    unsigned int* __restrict__ tdn, int* __restrict__ ntdn,
    unsigned int* __restrict__ pairs)
{
  const int t = threadIdx.x;
  for (int s = t; s < T_TOK; s += 256) {
    const unsigned int pv = (0x3F80u << 16) | (unsigned int)s;  // w=1.0 bf16
    pairs[32 * SLOT_CAP + s] = pv;
    pairs[33 * SLOT_CAP + s] = pv;
  }
  if (t == 0) {
    cnt[32] = T_TOK; cnt[33] = T_TOK;
    int b = 0, ngu = 0, ndn = 0;
    for (int e = 0; e < NE_ALL; ++e) {
      const int c = (e < 32) ? cnt[e] : T_TOK;
      base[e] = b;
      for (int m0 = 0; m0 < c; m0 += 128) {
        tgu[ngu++] = ((unsigned int)e << 16) | (unsigned int)m0;
        if (e < 33) tdn[ndn++] = ((unsigned int)e << 16) | (unsigned int)m0;
      }
      b += (c + 127) & ~127;
    }
    *ntgu = ngu; *ntdn = ndn;
  }
}

// ---------------------------------------------------------------------------
__global__ __launch_bounds__(256) void cvt_bf16_kernel(
    const float* __restrict__ in, unsigned short* __restrict__ out, int n4)
{
  int i = blockIdx.x * 256 + threadIdx.x;
  if (i >= n4) return;
  float4 v = ((const float4*)in)[i];
  ushort4 o;
  o.x = f2bf(v.x); o.y = f2bf(v.y); o.z = f2bf(v.z); o.w = f2bf(v.w);
  ((ushort4*)out)[i] = o;
}

// ---------------------------------------------------------------------------
// Fused transpose+cvt, 64(c) x 256(r) tiles, bf16 in LDS, uint4 stores.
// All 16 global loads are batched into registers BEFORE any LDS write
// (sched_barrier pins the separation) so a wave keeps 16 VMEM in flight —
// previous version interleaved load/write and serialized on HBM latency.
// ---------------------------------------------------------------------------
struct TDescTable {
  const float* in[6];
  unsigned short* out[6];
  int C[6];
  int ldout[6];
  long in_bs[6];
  long out_bs[6];
  int nbx[6];
  int nbxy[6];
  int start[7];
};

__global__ __launch_bounds__(256) void transpose_fused(TDescTable td)
{
  const int bid = blockIdx.x;
  int i = 0;
  while (i < 5 && bid >= td.start[i + 1]) ++i;
  const int local = bid - td.start[i];
  const int bz = local / td.nbxy[i];
  const int rem = local % td.nbxy[i];
  const int by = rem / td.nbx[i];
  const int bx = rem % td.nbx[i];
  const float* in = td.in[i] + (long)bz * td.in_bs[i];
  unsigned short* out = td.out[i] + (long)bz * td.out_bs[i];
  const int C = td.C[i], ldout = td.ldout[i];

  __shared__ unsigned short tile[64][258];
  const int c0 = bx * 64;
  const int r0 = by * 256;
  const int t = threadIdx.x;
  const int rl0 = t >> 4;          // 0..15
  const int cl0 = (t & 15) * 4;    // 0..60

  float4 v[16];
  #pragma unroll
  for (int p = 0; p < 16; ++p) {
    const int rl = p * 16 + rl0;
    v[p] = *(const float4*)(in + (long)(r0 + rl) * C + c0 + cl0);
  }
  __builtin_amdgcn_sched_barrier(0);   // keep all 16 loads issued first
  #pragma unroll
  for (int p = 0; p < 16; ++p) {
    const int rl = p * 16 + rl0;
    tile[cl0 + 0][rl] = f2bf(v[p].x);
    tile[cl0 + 1][rl] = f2bf(v[p].y);
    tile[cl0 + 2][rl] = f2bf(v[p].z);
    tile[cl0 + 3][rl] = f2bf(v[p].w);
  }
  __syncthreads();
  const int cw = t >> 5;           // 0..7
  const int rw = (t & 31) * 8;     // 0..248
  #pragma unroll
  for (int q = 0; q < 8; ++q) {
    const int cl = q * 8 + cw;
    const char* src = (const char*)&tile[cl][rw];  // 4B-aligned
    uint4 o;
    o.x = *(const unsigned int*)(src + 0);
    o.y = *(const unsigned int*)(src + 4);
    o.z = *(const unsigned int*)(src + 8);
    o.w = *(const unsigned int*)(src + 12);
    *(uint4*)(out + (long)(c0 + cl) * ldout + r0 + rw) = o;
  }
}

// ---------------------------------------------------------------------------
// Unified gate+up GEMM over GU tile list (routed + shared pseudo-experts),
// 512 thr (8 waves, 4Mx2N), tile 128x64, BK=64, 2-phase dbuf, XOR-swizzled
// LDS, gathered A rows; writes compact act[(base[e]+slot)][I].
// ---------------------------------------------------------------------------
__global__ __launch_bounds__(512, 4) void gate_up_moe_kernel(
    const unsigned short* __restrict__ xb,
    const unsigned short* __restrict__ bgT,
    const unsigned short* __restrict__ buT,
    const unsigned short* __restrict__ sgT,
    const unsigned short* __restrict__ suT,
    const int* __restrict__ cnt,
    const int* __restrict__ base,
    const unsigned int* __restrict__ pairs,
    const unsigned int* __restrict__ tiles,
    const int* __restrict__ ntp,
    unsigned short* __restrict__ act)
{
  const int ti = blockIdx.y;
  if (ti >= *ntp) return;
  const unsigned int tile = tiles[ti];
  const int e  = (int)(tile >> 16);
  const int m0 = (int)(tile & 0xFFFFu);
  const int cnte = cnt[e];
  const int be = base[e];
  const int n0 = blockIdx.x * 64;
  const long panel = (long)I_DIM * H_DIM;
  const unsigned short* Bg =
      ((e < 32) ? bgT + e * panel : sgT + (e - 32) * panel) + (long)n0 * H_DIM;
  const unsigned short* Bu =
      ((e < 32) ? buT + e * panel : suT + (e - 32) * panel) + (long)n0 * H_DIM;

  __shared__ unsigned short sA[2][128 * 64];
  __shared__ unsigned short sBg[2][64 * 64];
  __shared__ unsigned short sBu[2][64 * 64];

  const int tid = threadIdx.x;
  const int lane = tid & 63;
  const int wid = tid >> 6;
  const int wm = wid >> 1, wn = wid & 1;
  const int l15 = lane & 15;
  const int lk  = (lane >> 4) * 8;
  const int srow = tid >> 3;          // 0..63
  const int scol = (tid & 7) * 8;
  const int scolsw = (((tid & 7) ^ (srow & 7))) * 8;
  const int ksw = (l15 & 7) << 3;

  const unsigned short* asrc[2];
  #pragma unroll
  for (int r = 0; r < 2; ++r) {
    const int slot = m0 + r * 64 + srow;
    const unsigned int pr = (slot < cnte) ? pairs[e * SLOT_CAP + slot] : 0u;
    asrc[r] = xb + (long)(pr & 0xFFFFu) * H_DIM + scolsw;
  }

  const f32x4 fz = {0.f, 0.f, 0.f, 0.f};
  f32x4 accg[2][2], accu[2][2];
  #pragma unroll
  for (int i = 0; i < 2; ++i)
    #pragma unroll
    for (int j = 0; j < 2; ++j) { accg[i][j] = fz; accu[i][j] = fz; }

#define STAGE_GU(buf, k0) do {                                                 \
    gld16(asrc[0] + (k0), sA[buf] + srow * 64 + scol);                         \
    gld16(asrc[1] + (k0), sA[buf] + (64 + srow) * 64 + scol);                  \
    gld16(Bg + (long)srow * H_DIM + (k0) + scolsw,                             \
          sBg[buf] + srow * 64 + scol);                                        \
    gld16(Bu + (long)srow * H_DIM + (k0) + scolsw,                             \
          sBu[buf] + srow * 64 + scol);                                        \
  } while (0)

#define COMP_GU(buf) do {                                                      \
    __builtin_amdgcn_s_setprio(1);                                             \
    _Pragma("unroll")                                                          \
    for (int kk = 0; kk < 2; ++kk) {                                           \
      const int ko = kk * 32 + lk;                                             \
      bf16x8 a[2], g[2], u[2];                                                 \
      _Pragma("unroll")                                                        \
      for (int mi = 0; mi < 2; ++mi)                                           \
        a[mi] = *(const bf16x8*)(sA[buf] + (wm * 32 + mi * 16 + l15) * 64 +    \
                                 (ko ^ ksw));                                  \
      _Pragma("unroll")                                                        \
      for (int ni = 0; ni < 2; ++ni) {                                         \
        g[ni] = *(const bf16x8*)(sBg[buf] + (wn * 32 + ni * 16 + l15) * 64 +   \
                                 (ko ^ ksw));                                  \
        u[ni] = *(const bf16x8*)(sBu[buf] + (wn * 32 + ni * 16 + l15) * 64 +   \
                                 (ko ^ ksw));                                  \
      }                                                                        \
      _Pragma("unroll")                                                        \
      for (int mi = 0; mi < 2; ++mi)                                           \
        _Pragma("unroll")                                                      \
        for (int ni = 0; ni < 2; ++ni) {                                       \
          accg[mi][ni] = __builtin_amdgcn_mfma_f32_16x16x32_bf16(              \
              a[mi], g[ni], accg[mi][ni], 0, 0, 0);                            \
          accu[mi][ni] = __builtin_amdgcn_mfma_f32_16x16x32_bf16(              \
              a[mi], u[ni], accu[mi][ni], 0, 0, 0);                            \
        }                                                                      \
    }                                                                          \
    __builtin_amdgcn_s_setprio(0);                                             \
  } while (0)

  STAGE_GU(0, 0);
  __syncthreads();
  for (int t = 0; t < 32; t += 2) {
    if (t + 1 < 32) STAGE_GU(1, (t + 1) * 64);
    COMP_GU(0);
    __syncthreads();
    if (t + 2 < 32) STAGE_GU(0, (t + 2) * 64);
    COMP_GU(1);
    __syncthreads();
  }
#undef STAGE_GU
#undef COMP_GU

  const int colb = n0 + wn * 32;
  #pragma unroll
  for (int mi = 0; mi < 2; ++mi) {
    #pragma unroll
    for (int r = 0; r < 4; ++r) {
      const int slot = m0 + wm * 32 + mi * 16 + (lane >> 4) * 4 + r;
      if (slot < cnte) {
        const unsigned int pr = pairs[e * SLOT_CAP + slot];
        const float w = __uint_as_float(pr & 0xFFFF0000u);
        #pragma unroll
        for (int ni = 0; ni < 2; ++ni) {
          const float gv = accg[mi][ni][r];
          const float uv = accu[mi][ni][r];
          const float sv = (gv / (1.f + expf(-gv))) * uv * w;
          act[((long)(be + slot)) * I_DIM + colb + ni * 16 + l15] = f2bf(sv);
        }
      }
    }
  }
}

// ---------------------------------------------------------------------------
// Unified down GEMM over DN tile list; e=32 runs K=2048 spanning both shared
// act panels. atomicAdd-scatter onto zeroed out. 512 thr, tile 128x64,
// 2-phase dbuf, XOR-swizzled LDS.
// ---------------------------------------------------------------------------
__global__ __launch_bounds__(512, 4) void down_moe_kernel(
    const unsigned short* __restrict__ act,
    const unsigned short* __restrict__ wdT,
    const int* __restrict__ cnt,
    const int* __restrict__ base,
    const unsigned int* __restrict__ pairs,
    const unsigned int* __restrict__ tiles,
    const int* __restrict__ ntp,
    float* __restrict__ out)
{
  const int ti = blockIdx.y;
  if (ti >= *ntp) return;
  const unsigned int tile = tiles[ti];
  const int e  = (int)(tile >> 16);
  const int m0 = (int)(tile & 0xFFFFu);
  const int cnte = cnt[e];
  const int n0 = blockIdx.x * 64;
  const unsigned short* A = act + ((long)base[e] + m0) * I_DIM;
  const unsigned short* B = wdT + (long)n0 * K_TOT + (long)e * I_DIM;
  const int nk = (e == 32) ? 32 : 16;   // K-steps of 64

  __shared__ unsigned short sA[2][128 * 64];
  __shared__ unsigned short sB[2][64 * 64];

  const int tid = threadIdx.x;
  const int lane = tid & 63;
  const int wid = tid >> 6;
  const int wm = wid >> 1, wn = wid & 1;
  const int l15 = lane & 15;
  const int lk  = (lane >> 4) * 8;
  const int srow = tid >> 3;
  const int scol = (tid & 7) * 8;
  const int scolsw = (((tid & 7) ^ (srow & 7))) * 8;
  const int ksw = (l15 & 7) << 3;

  const f32x4 fz = {0.f, 0.f, 0.f, 0.f};
  f32x4 acc[2][2];
  #pragma unroll
  for (int i = 0; i < 2; ++i)
    #pragma unroll
    for (int j = 0; j < 2; ++j) acc[i][j] = fz;

#define STAGE_DN(buf, k0) do {                                                 \
    const long koff = (long)((k0) & 1023) +                                    \
                      (long)((k0) >> 10) * (2048L * 1024L);                    \
    gld16(A + (long)srow * I_DIM + koff + scolsw,                              \
          sA[buf] + srow * 64 + scol);                                         \
    gld16(A + (long)(64 + srow) * I_DIM + koff + scolsw,                       \
          sA[buf] + (64 + srow) * 64 + scol);                                  \
    gld16(B + (long)srow * K_TOT + (k0) + scolsw,                              \
          sB[buf] + srow * 64 + scol);                                         \
  } while (0)

#define COMP_DN(buf) do {                                                      \
    __builtin_amdgcn_s_setprio(1);                                             \
    _Pragma("unroll")                                                          \
    for (int kk = 0; kk < 2; ++kk) {                                           \
      const int ko = kk * 32 + lk;                                             \
      bf16x8 a[2], b[2];                                                       \
      _Pragma("unroll")                                                        \
      for (int mi = 0; mi < 2; ++mi)                                           \
        a[mi] = *(const bf16x8*)(sA[buf] + (wm * 32 + mi * 16 + l15) * 64 +    \
                                 (ko ^ ksw));                                  \
      _Pragma("unroll")                                                        \
      for (int ni = 0; ni < 2; ++ni)                                           \
        b[ni] = *(const bf16x8*)(sB[buf] + (wn * 32 + ni * 16 + l15) * 64 +    \
                                 (ko ^ ksw));                                  \
      _Pragma("unroll")                                                        \
      for (int mi = 0; mi < 2; ++mi)                                           \
        _Pragma("unroll")                                                      \
        for (int ni = 0; ni < 2; ++ni)                                         \
          acc[mi][ni] = __builtin_amdgcn_mfma_f32_16x16x32_bf16(               \
              a[mi], b[ni], acc[mi][ni], 0, 0, 0);                             \
    }                                                                          \
    __builtin_amdgcn_s_setprio(0);                                             \
  } while (0)

  STAGE_DN(0, 0);
  __syncthreads();
  for (int t = 0; t < 32; t += 2) {
    if (t >= nk) break;
    if (t + 1 < nk) STAGE_DN(1, (t + 1) * 64);
    COMP_DN(0);
    __syncthreads();
    if (t + 2 < nk) STAGE_DN(0, (t + 2) * 64);
    COMP_DN(1);
    __syncthreads();
  }
#undef STAGE_DN
#undef COMP_DN

  #pragma unroll
  for (int mi = 0; mi < 2; ++mi) {
    #pragma unroll
    for (int r = 0; r < 4; ++r) {
      const int slot = m0 + wm * 32 + mi * 16 + (lane >> 4) * 4 + r;
      if (slot < cnte) {
        const int tok = (int)(pairs[e * SLOT_CAP + slot] & 0xFFFFu);
        #pragma unroll
        for (int ni = 0; ni < 2; ++ni)
          atomicAdd(out + (long)tok * H_DIM + n0 + wn * 32 + ni * 16 + l15,
                    acc[mi][ni][r]);
      }
    }
  }
}

// ---------------------------------------------------------------------------
extern "C" void kernel_launch(void* const* d_in, const int* in_sizes, int n_in,
                              void* d_out, int out_size, void* d_ws, size_t ws_size,
                              hipStream_t stream) {
  (void)in_sizes; (void)n_in; (void)ws_size;
  const float* x   = (const float*)d_in[0];
  const float* gw  = (const float*)d_in[1];
  const float* wg  = (const float*)d_in[2];
  const float* wu  = (const float*)d_in[3];
  const float* wd  = (const float*)d_in[4];
  const float* wsg = (const float*)d_in[5];
  const float* wsu = (const float*)d_in[6];
  const float* wsd = (const float*)d_in[7];
  float* out = (float*)d_out;
  char* ws = (char*)d_ws;

  int*            cnt   = (int*)(ws + OFF_CNT);
  int*            ntgu  = (int*)(ws + OFF_NTGU);
  int*            ntdn  = (int*)(ws + OFF_NTDN);
  int*            basep = (int*)(ws + OFF_BASE);
  unsigned int*   tgu   = (unsigned int*)(ws + OFF_TGU);
  unsigned int*   tdn   = (unsigned int*)(ws + OFF_TDN);
  unsigned int*   pairs = (unsigned int*)(ws + OFF_PAIRS);
  unsigned short* xb    = (unsigned short*)(ws + OFF_XB);
  unsigned short* wgT   = (unsigned short*)(ws + OFF_WGT);
  unsigned short* wuT   = (unsigned short*)(ws + OFF_WUT);
  unsigned short* wsgT  = (unsigned short*)(ws + OFF_WSGT);
  unsigned short* wsuT  = (unsigned short*)(ws + OFF_WSUT);
  unsigned short* wdT   = (unsigned short*)(ws + OFF_WDT);
  unsigned short* actb  = (unsigned short*)(ws + OFF_ACT);

  hipMemsetAsync(ws + OFF_CNT, 0, 256, stream);           // cnt + nt
  hipMemsetAsync(out, 0, (size_t)out_size * sizeof(float), stream);

  router_kernel<<<T_TOK, 256, 0, stream>>>(x, gw, cnt, pairs);
  build_tiles_kernel<<<1, 256, 0, stream>>>(cnt, basep, tgu, ntgu, tdn, ntdn,
                                            pairs);
  cvt_bf16_kernel<<<(T_TOK * H_DIM / 4 + 255) / 256, 256, 0, stream>>>(
      x, xb, T_TOK * H_DIM / 4);

  // fused transpose+cvt of all 6 weight tensors (64c x 256r tiles)
  TDescTable td;
  // 0: wg [E][H][I] -> wgT [E][I][H]   (R=H=2048, C=I=1024)
  td.in[0] = wg;  td.out[0] = wgT;  td.C[0] = I_DIM;  td.ldout[0] = H_DIM;
  td.in_bs[0] = (long)H_DIM * I_DIM; td.out_bs[0] = (long)I_DIM * H_DIM;
  td.nbx[0] = I_DIM / 64; td.nbxy[0] = (I_DIM / 64) * (H_DIM / 256);
  // 1: wu -> wuT
  td.in[1] = wu;  td.out[1] = wuT;  td.C[1] = I_DIM;  td.ldout[1] = H_DIM;
  td.in_bs[1] = (long)H_DIM * I_DIM; td.out_bs[1] = (long)I_DIM * H_DIM;
  td.nbx[1] = I_DIM / 64; td.nbxy[1] = (I_DIM / 64) * (H_DIM / 256);
  // 2: wd [E][I][H] -> wdT cols [H][e*I..]   (R=I=1024, C=H=2048)
  td.in[2] = wd;  td.out[2] = wdT;  td.C[2] = H_DIM;  td.ldout[2] = K_TOT;
  td.in_bs[2] = (long)I_DIM * H_DIM; td.out_bs[2] = (long)I_DIM;
  td.nbx[2] = H_DIM / 64; td.nbxy[2] = (H_DIM / 64) * (I_DIM / 256);
  // 3: wsg [H][IS] -> wsgT [IS][H]
  td.in[3] = wsg; td.out[3] = wsgT; td.C[3] = IS_DIM; td.ldout[3] = H_DIM;
  td.in_bs[3] = 0; td.out_bs[3] = 0;
  td.nbx[3] = IS_DIM / 64; td.nbxy[3] = (IS_DIM / 64) * (H_DIM / 256);
  // 4: wsu -> wsuT
  td.in[4] = wsu; td.out[4] = wsuT; td.C[4] = IS_DIM; td.ldout[4] = H_DIM;
  td.in_bs[4] = 0; td.out_bs[4] = 0;
  td.nbx[4] = IS_DIM / 64; td.nbxy[4] = (IS_DIM / 64) * (H_DIM / 256);
  // 5: wsd [IS][H] -> wdT cols [H][32768..]
  td.in[5] = wsd; td.out[5] = wdT + E_NUM * I_DIM; td.C[5] = H_DIM;
  td.ldout[5] = K_TOT; td.in_bs[5] = 0; td.out_bs[5] = 0;
  td.nbx[5] = H_DIM / 64; td.nbxy[5] = (H_DIM / 64) * (IS_DIM / 256);
  td.start[0] = 0;
  for (int i = 0; i < 5; ++i) {
    int nz = (i <= 2) ? E_NUM : 1;
    td.start[i + 1] = td.start[i] + td.nbxy[i] * nz;
  }
  td.start[6] = td.start[5] + td.nbxy[5];
  transpose_fused<<<td.start[6], 256, 0, stream>>>(td);

  // unified gate+up (routed + shared pseudo-experts) -> compact act
  gate_up_moe_kernel<<<dim3(16, GU_TILES), 512, 0, stream>>>(
      xb, wgT, wuT, wsgT, wsuT, cnt, basep, pairs, tgu, ntgu, actb);

  // unified down (routed K=1024, shared K=2048) -> atomicAdd onto zeroed out
  down_moe_kernel<<<dim3(32, DN_TILES), 512, 0, stream>>>(
      actb, wdT, cnt, basep, pairs, tdn, ntdn, out);
}

// Round 9
// 844.512 us; speedup vs baseline: 1.1094x; 1.0009x over previous
//
#include <hip/hip_runtime.h>

// Problem dims (fixed by the reference)
#define T_TOK 2048      // B*S tokens
#define H_DIM 2048
#define E_NUM 32
#define I_DIM 1024
#define IS_DIM 2048
#define K_TOT (E_NUM * I_DIM + IS_DIM)   // 34816
#define SLOT_CAP 2048
#define NE_ALL 34        // 32 routed + 2 shared pseudo-experts
#define GU_TILES 192     // <=160 routed + 32 shared
#define DN_TILES 176     // <=160 routed + 16 shared (K=2048)
#define ACT_SLOTS 24576  // sum pad128(cnt_e) (<=20448) + 4096 shared

typedef __bf16 bf16x8 __attribute__((ext_vector_type(8)));
typedef float  f32x4  __attribute__((ext_vector_type(4)));
static_assert(sizeof(bf16x8) == 16, "bf16x8 must be 16B");

// Workspace layout (bytes). Total = 486,819,840.
#define OFF_CNT   ((size_t)0)            // cnt[34] int
#define OFF_NTGU  ((size_t)192)
#define OFF_NTDN  ((size_t)196)
#define OFF_BASE  ((size_t)256)          // base[34] int
#define OFF_TGU   ((size_t)512)          // tilesGU[192] uint
#define OFF_TDN   ((size_t)1280)         // tilesDN[176] uint
#define OFF_PAIRS ((size_t)2048)         // pairs[34][2048] uint = 278,528
#define OFF_XB    ((size_t)280576)       // xb [T,H] bf16 = 8,388,608
#define OFF_WGT   ((size_t)8669184)      // wgT [E][I][H] bf16
#define OFF_WUT   ((size_t)142886912)    // wuT [E][I][H] bf16
#define OFF_WSGT  ((size_t)277104640)    // wsgT [IS][H] bf16
#define OFF_WSUT  ((size_t)285493248)    // wsuT [IS][H] bf16
#define OFF_WDT   ((size_t)293881856)    // wdT [H][K_TOT] bf16
#define OFF_ACT   ((size_t)436488192)    // act [24576][1024] bf16 = 50,331,648

__device__ __forceinline__ unsigned short f2bf(float f) {
  unsigned int u = __float_as_uint(f);
  u += 0x7fffu + ((u >> 16) & 1u);   // round-to-nearest-even
  return (unsigned short)(u >> 16);
}

__device__ __forceinline__ void gld16(const void* g, void* l) {
  __builtin_amdgcn_global_load_lds(
      (const __attribute__((address_space(1))) unsigned int*)g,
      (__attribute__((address_space(3))) unsigned int*)l, 16, 0, 0);
}

#define WAITV(N) asm volatile("s_waitcnt vmcnt(" #N ")" ::: "memory")

// ---------------------------------------------------------------------------
// Router: scores = sigmoid(x @ gw^T); top-8; renorm; *2.5 -> pair lists.
// ---------------------------------------------------------------------------
__global__ __launch_bounds__(256) void router_kernel(
    const float* __restrict__ x, const float* __restrict__ gw,
    int* __restrict__ cnt, unsigned int* __restrict__ pairs)
{
  const int t = blockIdx.x;
  __shared__ float xs[H_DIM];
  __shared__ float sc[E_NUM];
  const float4* xr = (const float4*)(x + (long)t * H_DIM);
  for (int i = threadIdx.x; i < H_DIM / 4; i += 256) ((float4*)xs)[i] = xr[i];
  __syncthreads();
  const int e = threadIdx.x >> 3, p = threadIdx.x & 7;
  const float4* ga = (const float4*)(gw + (long)e * H_DIM);
  const float4* xa = (const float4*)xs;
  float s = 0.f;
  #pragma unroll 4
  for (int i = p * 64; i < p * 64 + 64; ++i) {
    float4 a = ga[i], b = xa[i];
    s += a.x * b.x + a.y * b.y + a.z * b.z + a.w * b.w;
  }
  s += __shfl_down(s, 4, 8);
  s += __shfl_down(s, 2, 8);
  s += __shfl_down(s, 1, 8);
  if (p == 0) sc[e] = 1.f / (1.f + expf(-s));
  __syncthreads();
  if (threadIdx.x == 0) {
    float v[E_NUM];
    #pragma unroll
    for (int i = 0; i < E_NUM; ++i) v[i] = sc[i];
    unsigned mask = 0; float sum = 0.f;
    int sel[8]; float wv[8];
    for (int k = 0; k < 8; ++k) {
      float best = -1.f; int bi = 0;
      for (int i = 0; i < E_NUM; ++i)
        if (!((mask >> i) & 1u) && v[i] > best) { best = v[i]; bi = i; }
      mask |= 1u << bi; sel[k] = bi; wv[k] = best; sum += best;
    }
    const float scale = 2.5f / (sum + 1e-20f);
    for (int k = 0; k < 8; ++k) {
      const int slot = atomicAdd(&cnt[sel[k]], 1);
      if (slot < SLOT_CAP) {
        const unsigned int w16 = (unsigned int)f2bf(wv[k] * scale);
        pairs[sel[k] * SLOT_CAP + slot] = (w16 << 16) | (unsigned int)t;
      }
    }
  }
}

// ---------------------------------------------------------------------------
// Build tile lists + per-expert act bases; fill shared pseudo-expert pairs.
// ---------------------------------------------------------------------------
__global__ __launch_bounds__(256) void build_tiles_kernel(
    int* __restrict__ cnt, int* __restrict__ base,
    unsigned int* __restrict__ tgu, int* __restrict__ ntgu,
    unsigned int* __restrict__ tdn, int* __restrict__ ntdn,
    unsigned int* __restrict__ pairs)
{
  const int t = threadIdx.x;
  for (int s = t; s < T_TOK; s += 256) {
    const unsigned int pv = (0x3F80u << 16) | (unsigned int)s;  // w=1.0 bf16
    pairs[32 * SLOT_CAP + s] = pv;
    pairs[33 * SLOT_CAP + s] = pv;
  }
  if (t == 0) {
    cnt[32] = T_TOK; cnt[33] = T_TOK;
    int b = 0, ngu = 0, ndn = 0;
    for (int e = 0; e < NE_ALL; ++e) {
      const int c = (e < 32) ? cnt[e] : T_TOK;
      base[e] = b;
      for (int m0 = 0; m0 < c; m0 += 128) {
        tgu[ngu++] = ((unsigned int)e << 16) | (unsigned int)m0;
        if (e < 33) tdn[ndn++] = ((unsigned int)e << 16) | (unsigned int)m0;
      }
      b += (c + 127) & ~127;
    }
    *ntgu = ngu; *ntdn = ndn;
  }
}

// ---------------------------------------------------------------------------
__global__ __launch_bounds__(256) void cvt_bf16_kernel(
    const float* __restrict__ in, unsigned short* __restrict__ out, int n4)
{
  int i = blockIdx.x * 256 + threadIdx.x;
  if (i >= n4) return;
  float4 v = ((const float4*)in)[i];
  ushort4 o;
  o.x = f2bf(v.x); o.y = f2bf(v.y); o.z = f2bf(v.z); o.w = f2bf(v.w);
  ((ushort4*)out)[i] = o;
}

// ---------------------------------------------------------------------------
// Fused transpose+cvt, 64(c) x 256(r) tiles, bf16 in LDS, uint4 stores.
// Measured at its mixed-stream roofline (~274us across 3 structurally
// different versions) — kept as-is.
// ---------------------------------------------------------------------------
struct TDescTable {
  const float* in[6];
  unsigned short* out[6];
  int C[6];
  int ldout[6];
  long in_bs[6];
  long out_bs[6];
  int nbx[6];
  int nbxy[6];
  int start[7];
};

__global__ __launch_bounds__(256) void transpose_fused(TDescTable td)
{
  const int bid = blockIdx.x;
  int i = 0;
  while (i < 5 && bid >= td.start[i + 1]) ++i;
  const int local = bid - td.start[i];
  const int bz = local / td.nbxy[i];
  const int rem = local % td.nbxy[i];
  const int by = rem / td.nbx[i];
  const int bx = rem % td.nbx[i];
  const float* in = td.in[i] + (long)bz * td.in_bs[i];
  unsigned short* out = td.out[i] + (long)bz * td.out_bs[i];
  const int C = td.C[i], ldout = td.ldout[i];

  __shared__ unsigned short tile[64][258];
  const int c0 = bx * 64;
  const int r0 = by * 256;
  const int t = threadIdx.x;
  const int rl0 = t >> 4;          // 0..15
  const int cl0 = (t & 15) * 4;    // 0..60

  float4 v[16];
  #pragma unroll
  for (int p = 0; p < 16; ++p) {
    const int rl = p * 16 + rl0;
    v[p] = *(const float4*)(in + (long)(r0 + rl) * C + c0 + cl0);
  }
  __builtin_amdgcn_sched_barrier(0);
  #pragma unroll
  for (int p = 0; p < 16; ++p) {
    const int rl = p * 16 + rl0;
    tile[cl0 + 0][rl] = f2bf(v[p].x);
    tile[cl0 + 1][rl] = f2bf(v[p].y);
    tile[cl0 + 2][rl] = f2bf(v[p].z);
    tile[cl0 + 3][rl] = f2bf(v[p].w);
  }
  __syncthreads();
  const int cw = t >> 5;           // 0..7
  const int rw = (t & 31) * 8;     // 0..248
  #pragma unroll
  for (int q = 0; q < 8; ++q) {
    const int cl = q * 8 + cw;
    const char* src = (const char*)&tile[cl][rw];  // 4B-aligned
    uint4 o;
    o.x = *(const unsigned int*)(src + 0);
    o.y = *(const unsigned int*)(src + 4);
    o.z = *(const unsigned int*)(src + 8);
    o.w = *(const unsigned int*)(src + 12);
    *(uint4*)(out + (long)(c0 + cl) * ldout + r0 + rw) = o;
  }
}

// ---------------------------------------------------------------------------
// Unified gate+up GEMM over GU tile list (routed + shared pseudo-experts),
// 512 thr (8 waves, 4Mx2N), tile 128x64, BK=64, XOR-swizzled LDS.
// COUNTED-vmcnt raw-barrier pipeline (T4): 3-deep staging, vmcnt(4) in the
// main loop (never 0), raw s_barrier (no compiler-forced full drain).
// ---------------------------------------------------------------------------
__global__ __launch_bounds__(512, 4) void gate_up_moe_kernel(
    const unsigned short* __restrict__ xb,
    const unsigned short* __restrict__ bgT,
    const unsigned short* __restrict__ buT,
    const unsigned short* __restrict__ sgT,
    const unsigned short* __restrict__ suT,
    const int* __restrict__ cnt,
    const int* __restrict__ base,
    const unsigned int* __restrict__ pairs,
    const unsigned int* __restrict__ tiles,
    const int* __restrict__ ntp,
    unsigned short* __restrict__ act)
{
  const int ti = blockIdx.y;
  if (ti >= *ntp) return;
  const unsigned int tile = tiles[ti];
  const int e  = (int)(tile >> 16);
  const int m0 = (int)(tile & 0xFFFFu);
  const int cnte = cnt[e];
  const int be = base[e];
  const int n0 = blockIdx.x * 64;
  const long panel = (long)I_DIM * H_DIM;
  const unsigned short* Bg =
      ((e < 32) ? bgT + e * panel : sgT + (e - 32) * panel) + (long)n0 * H_DIM;
  const unsigned short* Bu =
      ((e < 32) ? buT + e * panel : suT + (e - 32) * panel) + (long)n0 * H_DIM;

  __shared__ unsigned short sA[2][128 * 64];
  __shared__ unsigned short sBg[2][64 * 64];
  __shared__ unsigned short sBu[2][64 * 64];

  const int tid = threadIdx.x;
  const int lane = tid & 63;
  const int wid = tid >> 6;
  const int wm = wid >> 1, wn = wid & 1;
  const int l15 = lane & 15;
  const int lk  = (lane >> 4) * 8;
  const int srow = tid >> 3;          // 0..63
  const int scol = (tid & 7) * 8;
  const int scolsw = (((tid & 7) ^ (srow & 7))) * 8;
  const int ksw = (l15 & 7) << 3;

  const unsigned short* asrc[2];
  #pragma unroll
  for (int r = 0; r < 2; ++r) {
    const int slot = m0 + r * 64 + srow;
    const unsigned int pr = (slot < cnte) ? pairs[e * SLOT_CAP + slot] : 0u;
    asrc[r] = xb + (long)(pr & 0xFFFFu) * H_DIM + scolsw;
  }

  const f32x4 fz = {0.f, 0.f, 0.f, 0.f};
  f32x4 accg[2][2], accu[2][2];
  #pragma unroll
  for (int i = 0; i < 2; ++i)
    #pragma unroll
    for (int j = 0; j < 2; ++j) { accg[i][j] = fz; accu[i][j] = fz; }

#define STAGE_GU(buf, k0) do {                                                 \
    gld16(asrc[0] + (k0), sA[buf] + srow * 64 + scol);                         \
    gld16(asrc[1] + (k0), sA[buf] + (64 + srow) * 64 + scol);                  \
    gld16(Bg + (long)srow * H_DIM + (k0) + scolsw,                             \
          sBg[buf] + srow * 64 + scol);                                        \
    gld16(Bu + (long)srow * H_DIM + (k0) + scolsw,                             \
          sBu[buf] + srow * 64 + scol);                                        \
  } while (0)

#define COMP_GU(buf) do {                                                      \
    __builtin_amdgcn_s_setprio(1);                                             \
    _Pragma("unroll")                                                          \
    for (int kk = 0; kk < 2; ++kk) {                                           \
      const int ko = kk * 32 + lk;                                             \
      bf16x8 a[2], g[2], u[2];                                                 \
      _Pragma("unroll")                                                        \
      for (int mi = 0; mi < 2; ++mi)                                           \
        a[mi] = *(const bf16x8*)(sA[buf] + (wm * 32 + mi * 16 + l15) * 64 +    \
                                 (ko ^ ksw));                                  \
      _Pragma("unroll")                                                        \
      for (int ni = 0; ni < 2; ++ni) {                                         \
        g[ni] = *(const bf16x8*)(sBg[buf] + (wn * 32 + ni * 16 + l15) * 64 +   \
                                 (ko ^ ksw));                                  \
        u[ni] = *(const bf16x8*)(sBu[buf] + (wn * 32 + ni * 16 + l15) * 64 +   \
                                 (ko ^ ksw));                                  \
      }                                                                        \
      _Pragma("unroll")                                                        \
      for (int mi = 0; mi < 2; ++mi)                                           \
        _Pragma("unroll")                                                      \
        for (int ni = 0; ni < 2; ++ni) {                                       \
          accg[mi][ni] = __builtin_amdgcn_mfma_f32_16x16x32_bf16(              \
              a[mi], g[ni], accg[mi][ni], 0, 0, 0);                            \
          accu[mi][ni] = __builtin_amdgcn_mfma_f32_16x16x32_bf16(              \
              a[mi], u[ni], accu[mi][ni], 0, 0, 0);                            \
        }                                                                      \
    }                                                                          \
    __builtin_amdgcn_s_setprio(0);                                             \
  } while (0)

  // drain unrelated VMEM (pairs loads) so manual vmcnt counts only stages
  WAITV(0);
  STAGE_GU(0, 0);
  STAGE_GU(1, 64);
  for (int t = 0; t < 32; ++t) {
    const int cur = t & 1;
    if (t + 1 < 32) WAITV(4); else WAITV(0);   // buf[cur]'s 4 loads landed
    __builtin_amdgcn_s_barrier();
    __builtin_amdgcn_sched_barrier(0);
    COMP_GU(cur);
    __builtin_amdgcn_s_barrier();              // all waves done reading cur
    if (t + 2 < 32) STAGE_GU(cur, (t + 2) * 64);
  }
#undef STAGE_GU
#undef COMP_GU

  const int colb = n0 + wn * 32;
  #pragma unroll
  for (int mi = 0; mi < 2; ++mi) {
    #pragma unroll
    for (int r = 0; r < 4; ++r) {
      const int slot = m0 + wm * 32 + mi * 16 + (lane >> 4) * 4 + r;
      if (slot < cnte) {
        const unsigned int pr = pairs[e * SLOT_CAP + slot];
        const float w = __uint_as_float(pr & 0xFFFF0000u);
        #pragma unroll
        for (int ni = 0; ni < 2; ++ni) {
          const float gv = accg[mi][ni][r];
          const float uv = accu[mi][ni][r];
          const float sv = (gv / (1.f + expf(-gv))) * uv * w;
          act[((long)(be + slot)) * I_DIM + colb + ni * 16 + l15] = f2bf(sv);
        }
      }
    }
  }
}

// ---------------------------------------------------------------------------
// Unified down GEMM over DN tile list; e=32 runs K=2048 spanning both shared
// act panels. Same counted-vmcnt pipeline (3 loads/stage -> vmcnt(3)).
// atomicAdd-scatter onto zeroed out.
// ---------------------------------------------------------------------------
__global__ __launch_bounds__(512, 4) void down_moe_kernel(
    const unsigned short* __restrict__ act,
    const unsigned short* __restrict__ wdT,
    const int* __restrict__ cnt,
    const int* __restrict__ base,
    const unsigned int* __restrict__ pairs,
    const unsigned int* __restrict__ tiles,
    const int* __restrict__ ntp,
    float* __restrict__ out)
{
  const int ti = blockIdx.y;
  if (ti >= *ntp) return;
  const unsigned int tile = tiles[ti];
  const int e  = (int)(tile >> 16);
  const int m0 = (int)(tile & 0xFFFFu);
  const int cnte = cnt[e];
  const int n0 = blockIdx.x * 64;
  const unsigned short* A = act + ((long)base[e] + m0) * I_DIM;
  const unsigned short* B = wdT + (long)n0 * K_TOT + (long)e * I_DIM;
  const int nk = (e == 32) ? 32 : 16;   // K-steps of 64

  __shared__ unsigned short sA[2][128 * 64];
  __shared__ unsigned short sB[2][64 * 64];

  const int tid = threadIdx.x;
  const int lane = tid & 63;
  const int wid = tid >> 6;
  const int wm = wid >> 1, wn = wid & 1;
  const int l15 = lane & 15;
  const int lk  = (lane >> 4) * 8;
  const int srow = tid >> 3;
  const int scol = (tid & 7) * 8;
  const int scolsw = (((tid & 7) ^ (srow & 7))) * 8;
  const int ksw = (l15 & 7) << 3;

  const f32x4 fz = {0.f, 0.f, 0.f, 0.f};
  f32x4 acc[2][2];
  #pragma unroll
  for (int i = 0; i < 2; ++i)
    #pragma unroll
    for (int j = 0; j < 2; ++j) acc[i][j] = fz;

#define STAGE_DN(buf, k0) do {                                                 \
    const long koff = (long)((k0) & 1023) +                                    \
                      (long)((k0) >> 10) * (2048L * 1024L);                    \
    gld16(A + (long)srow * I_DIM + koff + scolsw,                              \
          sA[buf] + srow * 64 + scol);                                         \
    gld16(A + (long)(64 + srow) * I_DIM + koff + scolsw,                       \
          sA[buf] + (64 + srow) * 64 + scol);                                  \
    gld16(B + (long)srow * K_TOT + (k0) + scolsw,                              \
          sB[buf] + srow * 64 + scol);                                         \
  } while (0)

#define COMP_DN(buf) do {                                                      \
    __builtin_amdgcn_s_setprio(1);                                             \
    _Pragma("unroll")                                                          \
    for (int kk = 0; kk < 2; ++kk) {                                           \
      const int ko = kk * 32 + lk;                                             \
      bf16x8 a[2], b[2];                                                       \
      _Pragma("unroll")                                                        \
      for (int mi = 0; mi < 2; ++mi)                                           \
        a[mi] = *(const bf16x8*)(sA[buf] + (wm * 32 + mi * 16 + l15) * 64 +    \
                                 (ko ^ ksw));                                  \
      _Pragma("unroll")                                                        \
      for (int ni = 0; ni < 2; ++ni)                                           \
        b[ni] = *(const bf16x8*)(sB[buf] + (wn * 32 + ni * 16 + l15) * 64 +    \
                                 (ko ^ ksw));                                  \
      _Pragma("unroll")                                                        \
      for (int mi = 0; mi < 2; ++mi)                                           \
        _Pragma("unroll")                                                      \
        for (int ni = 0; ni < 2; ++ni)                                         \
          acc[mi][ni] = __builtin_amdgcn_mfma_f32_16x16x32_bf16(               \
              a[mi], b[ni], acc[mi][ni], 0, 0, 0);                             \
    }                                                                          \
    __builtin_amdgcn_s_setprio(0);                                             \
  } while (0)

  WAITV(0);
  STAGE_DN(0, 0);
  STAGE_DN(1, 64);
  for (int t = 0; t < nk; ++t) {
    const int cur = t & 1;
    if (t + 1 < nk) WAITV(3); else WAITV(0);
    __builtin_amdgcn_s_barrier();
    __builtin_amdgcn_sched_barrier(0);
    COMP_DN(cur);
    __builtin_amdgcn_s_barrier();
    if (t + 2 < nk) STAGE_DN(cur, (t + 2) * 64);
  }
#undef STAGE_DN
#undef COMP_DN

  #pragma unroll
  for (int mi = 0; mi < 2; ++mi) {
    #pragma unroll
    for (int r = 0; r < 4; ++r) {
      const int slot = m0 + wm * 32 + mi * 16 + (lane >> 4) * 4 + r;
      if (slot < cnte) {
        const int tok = (int)(pairs[e * SLOT_CAP + slot] & 0xFFFFu);
        #pragma unroll
        for (int ni = 0; ni < 2; ++ni)
          atomicAdd(out + (long)tok * H_DIM + n0 + wn * 32 + ni * 16 + l15,
                    acc[mi][ni][r]);
      }
    }
  }
}

// ---------------------------------------------------------------------------
extern "C" void kernel_launch(void* const* d_in, const int* in_sizes, int n_in,
                              void* d_out, int out_size, void* d_ws, size_t ws_size,
                              hipStream_t stream) {
  (void)in_sizes; (void)n_in; (void)ws_size;
  const float* x   = (const float*)d_in[0];
  const float* gw  = (const float*)d_in[1];
  const float* wg  = (const float*)d_in[2];
  const float* wu  = (const float*)d_in[3];
  const float* wd  = (const float*)d_in[4];
  const float* wsg = (const float*)d_in[5];
  const float* wsu = (const float*)d_in[6];
  const float* wsd = (const float*)d_in[7];
  float* out = (float*)d_out;
  char* ws = (char*)d_ws;

  int*            cnt   = (int*)(ws + OFF_CNT);
  int*            ntgu  = (int*)(ws + OFF_NTGU);
  int*            ntdn  = (int*)(ws + OFF_NTDN);
  int*            basep = (int*)(ws + OFF_BASE);
  unsigned int*   tgu   = (unsigned int*)(ws + OFF_TGU);
  unsigned int*   tdn   = (unsigned int*)(ws + OFF_TDN);
  unsigned int*   pairs = (unsigned int*)(ws + OFF_PAIRS);
  unsigned short* xb    = (unsigned short*)(ws + OFF_XB);
  unsigned short* wgT   = (unsigned short*)(ws + OFF_WGT);
  unsigned short* wuT   = (unsigned short*)(ws + OFF_WUT);
  unsigned short* wsgT  = (unsigned short*)(ws + OFF_WSGT);
  unsigned short* wsuT  = (unsigned short*)(ws + OFF_WSUT);
  unsigned short* wdT   = (unsigned short*)(ws + OFF_WDT);
  unsigned short* actb  = (unsigned short*)(ws + OFF_ACT);

  hipMemsetAsync(ws + OFF_CNT, 0, 256, stream);           // cnt + nt
  hipMemsetAsync(out, 0, (size_t)out_size * sizeof(float), stream);

  router_kernel<<<T_TOK, 256, 0, stream>>>(x, gw, cnt, pairs);
  build_tiles_kernel<<<1, 256, 0, stream>>>(cnt, basep, tgu, ntgu, tdn, ntdn,
                                            pairs);
  cvt_bf16_kernel<<<(T_TOK * H_DIM / 4 + 255) / 256, 256, 0, stream>>>(
      x, xb, T_TOK * H_DIM / 4);

  // fused transpose+cvt of all 6 weight tensors (64c x 256r tiles)
  TDescTable td;
  td.in[0] = wg;  td.out[0] = wgT;  td.C[0] = I_DIM;  td.ldout[0] = H_DIM;
  td.in_bs[0] = (long)H_DIM * I_DIM; td.out_bs[0] = (long)I_DIM * H_DIM;
  td.nbx[0] = I_DIM / 64; td.nbxy[0] = (I_DIM / 64) * (H_DIM / 256);
  td.in[1] = wu;  td.out[1] = wuT;  td.C[1] = I_DIM;  td.ldout[1] = H_DIM;
  td.in_bs[1] = (long)H_DIM * I_DIM; td.out_bs[1] = (long)I_DIM * H_DIM;
  td.nbx[1] = I_DIM / 64; td.nbxy[1] = (I_DIM / 64) * (H_DIM / 256);
  td.in[2] = wd;  td.out[2] = wdT;  td.C[2] = H_DIM;  td.ldout[2] = K_TOT;
  td.in_bs[2] = (long)I_DIM * H_DIM; td.out_bs[2] = (long)I_DIM;
  td.nbx[2] = H_DIM / 64; td.nbxy[2] = (H_DIM / 64) * (I_DIM / 256);
  td.in[3] = wsg; td.out[3] = wsgT; td.C[3] = IS_DIM; td.ldout[3] = H_DIM;
  td.in_bs[3] = 0; td.out_bs[3] = 0;
  td.nbx[3] = IS_DIM / 64; td.nbxy[3] = (IS_DIM / 64) * (H_DIM / 256);
  td.in[4] = wsu; td.out[4] = wsuT; td.C[4] = IS_DIM; td.ldout[4] = H_DIM;
  td.in_bs[4] = 0; td.out_bs[4] = 0;
  td.nbx[4] = IS_DIM / 64; td.nbxy[4] = (IS_DIM / 64) * (H_DIM / 256);
  td.in[5] = wsd; td.out[5] = wdT + E_NUM * I_DIM; td.C[5] = H_DIM;
  td.ldout[5] = K_TOT; td.in_bs[5] = 0; td.out_bs[5] = 0;
  td.nbx[5] = H_DIM / 64; td.nbxy[5] = (H_DIM / 64) * (IS_DIM / 256);
  td.start[0] = 0;
  for (int i = 0; i < 5; ++i) {
    int nz = (i <= 2) ? E_NUM : 1;
    td.start[i + 1] = td.start[i] + td.nbxy[i] * nz;
  }
  td.start[6] = td.start[5] + td.nbxy[5];
  transpose_fused<<<td.start[6], 256, 0, stream>>>(td);

  // unified gate+up (routed + shared pseudo-experts) -> compact act
  gate_up_moe_kernel<<<dim3(16, GU_TILES), 512, 0, stream>>>(
      xb, wgT, wuT, wsgT, wsuT, cnt, basep, pairs, tgu, ntgu, actb);

  // unified down (routed K=1024, shared K=2048) -> atomicAdd onto zeroed out
  down_moe_kernel<<<dim3(32, DN_TILES), 512, 0, stream>>>(
      actb, wdT, cnt, basep, pairs, tdn, ntdn, out);
}

// Round 10
// 836.975 us; speedup vs baseline: 1.1194x; 1.0090x over previous
//
#include <hip/hip_runtime.h>

// Problem dims (fixed by the reference)
#define T_TOK 2048      // B*S tokens
#define H_DIM 2048
#define E_NUM 32
#define I_DIM 1024
#define IS_DIM 2048
#define K_TOT (E_NUM * I_DIM + IS_DIM)   // 34816
#define SLOT_CAP 2048
#define NE_ALL 34        // 32 routed + 2 shared pseudo-experts
#define GU_TILES 192     // <=160 routed + 32 shared
#define DN_TILES 176     // <=160 routed + 16 shared (K=2048)
#define ACT_SLOTS 24576  // sum pad128(cnt_e) (<=20448) + 4096 shared

typedef __bf16 bf16x8 __attribute__((ext_vector_type(8)));
typedef float  f32x4  __attribute__((ext_vector_type(4)));
static_assert(sizeof(bf16x8) == 16, "bf16x8 must be 16B");

// Workspace layout (bytes). Total = 486,819,840.
#define OFF_CNT   ((size_t)0)            // cnt[34] int
#define OFF_NTGU  ((size_t)192)
#define OFF_NTDN  ((size_t)196)
#define OFF_BASE  ((size_t)256)          // base[34] int
#define OFF_TGU   ((size_t)512)          // tilesGU[192] uint
#define OFF_TDN   ((size_t)1280)         // tilesDN[176] uint
#define OFF_PAIRS ((size_t)2048)         // pairs[34][2048] uint = 278,528
#define OFF_XB    ((size_t)280576)       // xb [T,H] bf16 = 8,388,608
#define OFF_WGT   ((size_t)8669184)      // wgT [E][I][H] bf16
#define OFF_WUT   ((size_t)142886912)    // wuT [E][I][H] bf16
#define OFF_WSGT  ((size_t)277104640)    // wsgT [IS][H] bf16
#define OFF_WSUT  ((size_t)285493248)    // wsuT [IS][H] bf16
#define OFF_WDT   ((size_t)293881856)    // wdT [H][K_TOT] bf16
#define OFF_ACT   ((size_t)436488192)    // act [24576][1024] bf16 = 50,331,648

__device__ __forceinline__ unsigned short f2bf(float f) {
  unsigned int u = __float_as_uint(f);
  u += 0x7fffu + ((u >> 16) & 1u);   // round-to-nearest-even
  return (unsigned short)(u >> 16);
}

__device__ __forceinline__ void gld16(const void* g, void* l) {
  __builtin_amdgcn_global_load_lds(
      (const __attribute__((address_space(1))) unsigned int*)g,
      (__attribute__((address_space(3))) unsigned int*)l, 16, 0, 0);
}

// ---------------------------------------------------------------------------
// Router: scores = sigmoid(x @ gw^T); top-8; renorm; *2.5 -> pair lists.
// ---------------------------------------------------------------------------
__global__ __launch_bounds__(256) void router_kernel(
    const float* __restrict__ x, const float* __restrict__ gw,
    int* __restrict__ cnt, unsigned int* __restrict__ pairs)
{
  const int t = blockIdx.x;
  __shared__ float xs[H_DIM];
  __shared__ float sc[E_NUM];
  const float4* xr = (const float4*)(x + (long)t * H_DIM);
  for (int i = threadIdx.x; i < H_DIM / 4; i += 256) ((float4*)xs)[i] = xr[i];
  __syncthreads();
  const int e = threadIdx.x >> 3, p = threadIdx.x & 7;
  const float4* ga = (const float4*)(gw + (long)e * H_DIM);
  const float4* xa = (const float4*)xs;
  float s = 0.f;
  #pragma unroll 4
  for (int i = p * 64; i < p * 64 + 64; ++i) {
    float4 a = ga[i], b = xa[i];
    s += a.x * b.x + a.y * b.y + a.z * b.z + a.w * b.w;
  }
  s += __shfl_down(s, 4, 8);
  s += __shfl_down(s, 2, 8);
  s += __shfl_down(s, 1, 8);
  if (p == 0) sc[e] = 1.f / (1.f + expf(-s));
  __syncthreads();
  if (threadIdx.x == 0) {
    float v[E_NUM];
    #pragma unroll
    for (int i = 0; i < E_NUM; ++i) v[i] = sc[i];
    unsigned mask = 0; float sum = 0.f;
    int sel[8]; float wv[8];
    for (int k = 0; k < 8; ++k) {
      float best = -1.f; int bi = 0;
      for (int i = 0; i < E_NUM; ++i)
        if (!((mask >> i) & 1u) && v[i] > best) { best = v[i]; bi = i; }
      mask |= 1u << bi; sel[k] = bi; wv[k] = best; sum += best;
    }
    const float scale = 2.5f / (sum + 1e-20f);
    for (int k = 0; k < 8; ++k) {
      const int slot = atomicAdd(&cnt[sel[k]], 1);
      if (slot < SLOT_CAP) {
        const unsigned int w16 = (unsigned int)f2bf(wv[k] * scale);
        pairs[sel[k] * SLOT_CAP + slot] = (w16 << 16) | (unsigned int)t;
      }
    }
  }
}

// ---------------------------------------------------------------------------
// Build tile lists + per-expert act bases; fill shared pseudo-expert pairs.
// ---------------------------------------------------------------------------
__global__ __launch_bounds__(256) void build_tiles_kernel(
    int* __restrict__ cnt, int* __restrict__ base,
    unsigned int* __restrict__ tgu, int* __restrict__ ntgu,
    unsigned int* __restrict__ tdn, int* __restrict__ ntdn,
    unsigned int* __restrict__ pairs)
{
  const int t = threadIdx.x;
  for (int s = t; s < T_TOK; s += 256) {
    const unsigned int pv = (0x3F80u << 16) | (unsigned int)s;  // w=1.0 bf16
    pairs[32 * SLOT_CAP + s] = pv;
    pairs[33 * SLOT_CAP + s] = pv;
  }
  if (t == 0) {
    cnt[32] = T_TOK; cnt[33] = T_TOK;
    int b = 0, ngu = 0, ndn = 0;
    for (int e = 0; e < NE_ALL; ++e) {
      const int c = (e < 32) ? cnt[e] : T_TOK;
      base[e] = b;
      for (int m0 = 0; m0 < c; m0 += 128) {
        tgu[ngu++] = ((unsigned int)e << 16) | (unsigned int)m0;
        if (e < 33) tdn[ndn++] = ((unsigned int)e << 16) | (unsigned int)m0;
      }
      b += (c + 127) & ~127;
    }
    *ntgu = ngu; *ntdn = ndn;
  }
}

// ---------------------------------------------------------------------------
__global__ __launch_bounds__(256) void cvt_bf16_kernel(
    const float* __restrict__ in, unsigned short* __restrict__ out, int n4)
{
  int i = blockIdx.x * 256 + threadIdx.x;
  if (i >= n4) return;
  float4 v = ((const float4*)in)[i];
  ushort4 o;
  o.x = f2bf(v.x); o.y = f2bf(v.y); o.z = f2bf(v.z); o.w = f2bf(v.w);
  ((ushort4*)out)[i] = o;
}

// ---------------------------------------------------------------------------
// Fused transpose+cvt, 64(c) x 256(r) tiles — measured at its mixed-stream
// limit (~274us across 3 variants); kept as-is.
// ---------------------------------------------------------------------------
struct TDescTable {
  const float* in[6];
  unsigned short* out[6];
  int C[6];
  int ldout[6];
  long in_bs[6];
  long out_bs[6];
  int nbx[6];
  int nbxy[6];
  int start[7];
};

__global__ __launch_bounds__(256) void transpose_fused(TDescTable td)
{
  const int bid = blockIdx.x;
  int i = 0;
  while (i < 5 && bid >= td.start[i + 1]) ++i;
  const int local = bid - td.start[i];
  const int bz = local / td.nbxy[i];
  const int rem = local % td.nbxy[i];
  const int by = rem / td.nbx[i];
  const int bx = rem % td.nbx[i];
  const float* in = td.in[i] + (long)bz * td.in_bs[i];
  unsigned short* out = td.out[i] + (long)bz * td.out_bs[i];
  const int C = td.C[i], ldout = td.ldout[i];

  __shared__ unsigned short tile[64][258];
  const int c0 = bx * 64;
  const int r0 = by * 256;
  const int t = threadIdx.x;
  const int rl0 = t >> 4;          // 0..15
  const int cl0 = (t & 15) * 4;    // 0..60

  float4 v[16];
  #pragma unroll
  for (int p = 0; p < 16; ++p) {
    const int rl = p * 16 + rl0;
    v[p] = *(const float4*)(in + (long)(r0 + rl) * C + c0 + cl0);
  }
  __builtin_amdgcn_sched_barrier(0);
  #pragma unroll
  for (int p = 0; p < 16; ++p) {
    const int rl = p * 16 + rl0;
    tile[cl0 + 0][rl] = f2bf(v[p].x);
    tile[cl0 + 1][rl] = f2bf(v[p].y);
    tile[cl0 + 2][rl] = f2bf(v[p].z);
    tile[cl0 + 3][rl] = f2bf(v[p].w);
  }
  __syncthreads();
  const int cw = t >> 5;           // 0..7
  const int rw = (t & 31) * 8;     // 0..248
  #pragma unroll
  for (int q = 0; q < 8; ++q) {
    const int cl = q * 8 + cw;
    const char* src = (const char*)&tile[cl][rw];  // 4B-aligned
    uint4 o;
    o.x = *(const unsigned int*)(src + 0);
    o.y = *(const unsigned int*)(src + 4);
    o.z = *(const unsigned int*)(src + 8);
    o.w = *(const unsigned int*)(src + 12);
    *(uint4*)(out + (long)(c0 + cl) * ldout + r0 + rw) = o;
  }
}

// ---------------------------------------------------------------------------
// Unified gate+up GEMM over GU tile list. Round-2-proven geometry: 256 thr,
// 4 waves (2Mx2N), wave tile 64x32, block 128x64, single-buffered 32KB LDS,
// 2-barrier K-loop, XOR-swizzled LDS, gathered A rows, setprio around MFMA.
// ---------------------------------------------------------------------------
__global__ __launch_bounds__(256) void gate_up_moe_kernel(
    const unsigned short* __restrict__ xb,
    const unsigned short* __restrict__ bgT,
    const unsigned short* __restrict__ buT,
    const unsigned short* __restrict__ sgT,
    const unsigned short* __restrict__ suT,
    const int* __restrict__ cnt,
    const int* __restrict__ base,
    const unsigned int* __restrict__ pairs,
    const unsigned int* __restrict__ tiles,
    const int* __restrict__ ntp,
    unsigned short* __restrict__ act)
{
  const int ti = blockIdx.y;
  if (ti >= *ntp) return;
  const unsigned int tile = tiles[ti];
  const int e  = (int)(tile >> 16);
  const int m0 = (int)(tile & 0xFFFFu);
  const int cnte = cnt[e];
  const int be = base[e];
  const int n0 = blockIdx.x * 64;
  const long panel = (long)I_DIM * H_DIM;
  const unsigned short* Bg =
      ((e < 32) ? bgT + e * panel : sgT + (e - 32) * panel) + (long)n0 * H_DIM;
  const unsigned short* Bu =
      ((e < 32) ? buT + e * panel : suT + (e - 32) * panel) + (long)n0 * H_DIM;

  __shared__ unsigned short sA[128 * 64];
  __shared__ unsigned short sBg[64 * 64];
  __shared__ unsigned short sBu[64 * 64];

  const int tid = threadIdx.x;
  const int lane = tid & 63;
  const int wid = tid >> 6;
  const int wm = wid >> 1, wn = wid & 1;
  const int l15 = lane & 15;
  const int lk  = (lane >> 4) * 8;
  const int srow = tid >> 3;                       // 0..31
  const int scol = (tid & 7) * 8;
  const int scolsw = (((tid & 7) ^ (srow & 7))) * 8;
  const int ksw = (l15 & 7) << 3;

  const unsigned short* asrc[4];
  #pragma unroll
  for (int r = 0; r < 4; ++r) {
    const int slot = m0 + r * 32 + srow;
    const unsigned int pr = (slot < cnte) ? pairs[e * SLOT_CAP + slot] : 0u;
    asrc[r] = xb + (long)(pr & 0xFFFFu) * H_DIM + scolsw;
  }

  const f32x4 fz = {0.f, 0.f, 0.f, 0.f};
  f32x4 accg[4][2], accu[4][2];
  #pragma unroll
  for (int i = 0; i < 4; ++i)
    #pragma unroll
    for (int j = 0; j < 2; ++j) { accg[i][j] = fz; accu[i][j] = fz; }

  for (int k0 = 0; k0 < H_DIM; k0 += 64) {
    #pragma unroll
    for (int r = 0; r < 4; ++r)
      gld16(asrc[r] + k0, sA + (r * 32 + srow) * 64 + scol);
    #pragma unroll
    for (int r = 0; r < 2; ++r) {
      gld16(Bg + (long)(r * 32 + srow) * H_DIM + k0 + scolsw,
            sBg + (r * 32 + srow) * 64 + scol);
      gld16(Bu + (long)(r * 32 + srow) * H_DIM + k0 + scolsw,
            sBu + (r * 32 + srow) * 64 + scol);
    }
    __syncthreads();
    __builtin_amdgcn_s_setprio(1);
    #pragma unroll
    for (int kk = 0; kk < 2; ++kk) {
      const int ko = kk * 32 + lk;
      bf16x8 a[4], g[2], u[2];
      #pragma unroll
      for (int mi = 0; mi < 4; ++mi)
        a[mi] = *(const bf16x8*)(sA + (wm * 64 + mi * 16 + l15) * 64 + (ko ^ ksw));
      #pragma unroll
      for (int ni = 0; ni < 2; ++ni) {
        g[ni] = *(const bf16x8*)(sBg + (wn * 32 + ni * 16 + l15) * 64 + (ko ^ ksw));
        u[ni] = *(const bf16x8*)(sBu + (wn * 32 + ni * 16 + l15) * 64 + (ko ^ ksw));
      }
      #pragma unroll
      for (int mi = 0; mi < 4; ++mi)
        #pragma unroll
        for (int ni = 0; ni < 2; ++ni) {
          accg[mi][ni] = __builtin_amdgcn_mfma_f32_16x16x32_bf16(a[mi], g[ni], accg[mi][ni], 0, 0, 0);
          accu[mi][ni] = __builtin_amdgcn_mfma_f32_16x16x32_bf16(a[mi], u[ni], accu[mi][ni], 0, 0, 0);
        }
    }
    __builtin_amdgcn_s_setprio(0);
    __syncthreads();
  }

  const int colb = n0 + wn * 32;
  #pragma unroll
  for (int mi = 0; mi < 4; ++mi) {
    #pragma unroll
    for (int r = 0; r < 4; ++r) {
      const int slot = m0 + wm * 64 + mi * 16 + (lane >> 4) * 4 + r;
      if (slot < cnte) {
        const unsigned int pr = pairs[e * SLOT_CAP + slot];
        const float w = __uint_as_float(pr & 0xFFFF0000u);
        #pragma unroll
        for (int ni = 0; ni < 2; ++ni) {
          const float gv = accg[mi][ni][r];
          const float uv = accu[mi][ni][r];
          const float sv = (gv / (1.f + expf(-gv))) * uv * w;
          act[((long)(be + slot)) * I_DIM + colb + ni * 16 + l15] = f2bf(sv);
        }
      }
    }
  }
}

// ---------------------------------------------------------------------------
// Unified down GEMM over DN tile list. 256 thr, 4 waves (2Mx2N), wave tile
// 64x64, block 128(M)x128(N), single-buf 32KB LDS, 2-barrier loop.
// e=32 runs K=2048 spanning both shared act panels. atomicAdd onto zeroed out.
// ---------------------------------------------------------------------------
__global__ __launch_bounds__(256) void down_moe_kernel(
    const unsigned short* __restrict__ act,
    const unsigned short* __restrict__ wdT,
    const int* __restrict__ cnt,
    const int* __restrict__ base,
    const unsigned int* __restrict__ pairs,
    const unsigned int* __restrict__ tiles,
    const int* __restrict__ ntp,
    float* __restrict__ out)
{
  const int ti = blockIdx.y;
  if (ti >= *ntp) return;
  const unsigned int tile = tiles[ti];
  const int e  = (int)(tile >> 16);
  const int m0 = (int)(tile & 0xFFFFu);
  const int cnte = cnt[e];
  const int n0 = blockIdx.x * 128;
  const unsigned short* A = act + ((long)base[e] + m0) * I_DIM;
  const unsigned short* B = wdT + (long)n0 * K_TOT + (long)e * I_DIM;
  const int nk = (e == 32) ? 32 : 16;   // K-steps of 64

  __shared__ unsigned short sA[128 * 64];
  __shared__ unsigned short sB[128 * 64];

  const int tid = threadIdx.x;
  const int lane = tid & 63;
  const int wid = tid >> 6;
  const int wm = wid >> 1, wn = wid & 1;
  const int l15 = lane & 15;
  const int lk  = (lane >> 4) * 8;
  const int srow = tid >> 3;                       // 0..31
  const int scol = (tid & 7) * 8;
  const int scolsw = (((tid & 7) ^ (srow & 7))) * 8;
  const int ksw = (l15 & 7) << 3;

  const f32x4 fz = {0.f, 0.f, 0.f, 0.f};
  f32x4 acc[4][4];
  #pragma unroll
  for (int i = 0; i < 4; ++i)
    #pragma unroll
    for (int j = 0; j < 4; ++j) acc[i][j] = fz;

  for (int t = 0; t < nk; ++t) {
    const int k0 = t * 64;
    const long koff = (long)(k0 & 1023) + (long)(k0 >> 10) * (2048L * 1024L);
    #pragma unroll
    for (int r = 0; r < 4; ++r)
      gld16(A + (long)(r * 32 + srow) * I_DIM + koff + scolsw,
            sA + (r * 32 + srow) * 64 + scol);
    #pragma unroll
    for (int r = 0; r < 4; ++r)
      gld16(B + (long)(r * 32 + srow) * K_TOT + k0 + scolsw,
            sB + (r * 32 + srow) * 64 + scol);
    __syncthreads();
    __builtin_amdgcn_s_setprio(1);
    #pragma unroll
    for (int kk = 0; kk < 2; ++kk) {
      const int ko = kk * 32 + lk;
      bf16x8 a[4], b[4];
      #pragma unroll
      for (int mi = 0; mi < 4; ++mi)
        a[mi] = *(const bf16x8*)(sA + (wm * 64 + mi * 16 + l15) * 64 + (ko ^ ksw));
      #pragma unroll
      for (int ni = 0; ni < 4; ++ni)
        b[ni] = *(const bf16x8*)(sB + (wn * 64 + ni * 16 + l15) * 64 + (ko ^ ksw));
      #pragma unroll
      for (int mi = 0; mi < 4; ++mi)
        #pragma unroll
        for (int ni = 0; ni < 4; ++ni)
          acc[mi][ni] = __builtin_amdgcn_mfma_f32_16x16x32_bf16(a[mi], b[ni], acc[mi][ni], 0, 0, 0);
    }
    __builtin_amdgcn_s_setprio(0);
    __syncthreads();
  }

  #pragma unroll
  for (int mi = 0; mi < 4; ++mi) {
    #pragma unroll
    for (int r = 0; r < 4; ++r) {
      const int slot = m0 + wm * 64 + mi * 16 + (lane >> 4) * 4 + r;
      if (slot < cnte) {
        const int tok = (int)(pairs[e * SLOT_CAP + slot] & 0xFFFFu);
        #pragma unroll
        for (int ni = 0; ni < 4; ++ni)
          atomicAdd(out + (long)tok * H_DIM + n0 + wn * 64 + ni * 16 + l15,
                    acc[mi][ni][r]);
      }
    }
  }
}

// ---------------------------------------------------------------------------
extern "C" void kernel_launch(void* const* d_in, const int* in_sizes, int n_in,
                              void* d_out, int out_size, void* d_ws, size_t ws_size,
                              hipStream_t stream) {
  (void)in_sizes; (void)n_in; (void)ws_size;
  const float* x   = (const float*)d_in[0];
  const float* gw  = (const float*)d_in[1];
  const float* wg  = (const float*)d_in[2];
  const float* wu  = (const float*)d_in[3];
  const float* wd  = (const float*)d_in[4];
  const float* wsg = (const float*)d_in[5];
  const float* wsu = (const float*)d_in[6];
  const float* wsd = (const float*)d_in[7];
  float* out = (float*)d_out;
  char* ws = (char*)d_ws;

  int*            cnt   = (int*)(ws + OFF_CNT);
  int*            ntgu  = (int*)(ws + OFF_NTGU);
  int*            ntdn  = (int*)(ws + OFF_NTDN);
  int*            basep = (int*)(ws + OFF_BASE);
  unsigned int*   tgu   = (unsigned int*)(ws + OFF_TGU);
  unsigned int*   tdn   = (unsigned int*)(ws + OFF_TDN);
  unsigned int*   pairs = (unsigned int*)(ws + OFF_PAIRS);
  unsigned short* xb    = (unsigned short*)(ws + OFF_XB);
  unsigned short* wgT   = (unsigned short*)(ws + OFF_WGT);
  unsigned short* wuT   = (unsigned short*)(ws + OFF_WUT);
  unsigned short* wsgT  = (unsigned short*)(ws + OFF_WSGT);
  unsigned short* wsuT  = (unsigned short*)(ws + OFF_WSUT);
  unsigned short* wdT   = (unsigned short*)(ws + OFF_WDT);
  unsigned short* actb  = (unsigned short*)(ws + OFF_ACT);

  hipMemsetAsync(ws + OFF_CNT, 0, 256, stream);           // cnt + nt
  hipMemsetAsync(out, 0, (size_t)out_size * sizeof(float), stream);

  router_kernel<<<T_TOK, 256, 0, stream>>>(x, gw, cnt, pairs);
  build_tiles_kernel<<<1, 256, 0, stream>>>(cnt, basep, tgu, ntgu, tdn, ntdn,
                                            pairs);
  cvt_bf16_kernel<<<(T_TOK * H_DIM / 4 + 255) / 256, 256, 0, stream>>>(
      x, xb, T_TOK * H_DIM / 4);

  // fused transpose+cvt of all 6 weight tensors (64c x 256r tiles)
  TDescTable td;
  td.in[0] = wg;  td.out[0] = wgT;  td.C[0] = I_DIM;  td.ldout[0] = H_DIM;
  td.in_bs[0] = (long)H_DIM * I_DIM; td.out_bs[0] = (long)I_DIM * H_DIM;
  td.nbx[0] = I_DIM / 64; td.nbxy[0] = (I_DIM / 64) * (H_DIM / 256);
  td.in[1] = wu;  td.out[1] = wuT;  td.C[1] = I_DIM;  td.ldout[1] = H_DIM;
  td.in_bs[1] = (long)H_DIM * I_DIM; td.out_bs[1] = (long)I_DIM * H_DIM;
  td.nbx[1] = I_DIM / 64; td.nbxy[1] = (I_DIM / 64) * (H_DIM / 256);
  td.in[2] = wd;  td.out[2] = wdT;  td.C[2] = H_DIM;  td.ldout[2] = K_TOT;
  td.in_bs[2] = (long)I_DIM * H_DIM; td.out_bs[2] = (long)I_DIM;
  td.nbx[2] = H_DIM / 64; td.nbxy[2] = (H_DIM / 64) * (I_DIM / 256);
  td.in[3] = wsg; td.out[3] = wsgT; td.C[3] = IS_DIM; td.ldout[3] = H_DIM;
  td.in_bs[3] = 0; td.out_bs[3] = 0;
  td.nbx[3] = IS_DIM / 64; td.nbxy[3] = (IS_DIM / 64) * (H_DIM / 256);
  td.in[4] = wsu; td.out[4] = wsuT; td.C[4] = IS_DIM; td.ldout[4] = H_DIM;
  td.in_bs[4] = 0; td.out_bs[4] = 0;
  td.nbx[4] = IS_DIM / 64; td.nbxy[4] = (IS_DIM / 64) * (H_DIM / 256);
  td.in[5] = wsd; td.out[5] = wdT + E_NUM * I_DIM; td.C[5] = H_DIM;
  td.ldout[5] = K_TOT; td.in_bs[5] = 0; td.out_bs[5] = 0;
  td.nbx[5] = H_DIM / 64; td.nbxy[5] = (H_DIM / 64) * (IS_DIM / 256);
  td.start[0] = 0;
  for (int i = 0; i < 5; ++i) {
    int nz = (i <= 2) ? E_NUM : 1;
    td.start[i + 1] = td.start[i] + td.nbxy[i] * nz;
  }
  td.start[6] = td.start[5] + td.nbxy[5];
  transpose_fused<<<td.start[6], 256, 0, stream>>>(td);

  // unified gate+up (routed + shared pseudo-experts) -> compact act
  gate_up_moe_kernel<<<dim3(16, GU_TILES), 256, 0, stream>>>(
      xb, wgT, wuT, wsgT, wsuT, cnt, basep, pairs, tgu, ntgu, actb);

  // unified down (routed K=1024, shared K=2048) -> atomicAdd onto zeroed out
  down_moe_kernel<<<dim3(16, DN_TILES), 256, 0, stream>>>(
      actb, wdT, cnt, basep, pairs, tdn, ntdn, out);
}

// Round 11
// 833.084 us; speedup vs baseline: 1.1246x; 1.0047x over previous
//
#include <hip/hip_runtime.h>

// Problem dims (fixed by the reference)
#define T_TOK 2048      // B*S tokens
#define H_DIM 2048
#define E_NUM 32
#define I_DIM 1024
#define IS_DIM 2048
#define K_TOT (E_NUM * I_DIM + IS_DIM)   // 34816
#define SLOT_CAP 2048
#define NE_ALL 34        // 32 routed + 2 shared pseudo-experts
#define GU_TILES 192     // <=160 routed + 32 shared
#define DN_TILES 176     // <=160 routed + 16 shared (K=2048)
#define ACT_SLOTS 24576  // sum pad128(cnt_e) (<=20448) + 4096 shared

typedef __bf16 bf16x8 __attribute__((ext_vector_type(8)));
typedef float  f32x4  __attribute__((ext_vector_type(4)));
static_assert(sizeof(bf16x8) == 16, "bf16x8 must be 16B");

// Workspace layout (bytes). Total = 486,819,840.
#define OFF_CNT   ((size_t)0)            // cnt[34] int
#define OFF_NTGU  ((size_t)192)
#define OFF_NTDN  ((size_t)196)
#define OFF_BASE  ((size_t)256)          // base[34] int
#define OFF_TGU   ((size_t)512)          // tilesGU[192] uint
#define OFF_TDN   ((size_t)1280)         // tilesDN[176] uint
#define OFF_PAIRS ((size_t)2048)         // pairs[34][2048] uint = 278,528
#define OFF_XB    ((size_t)280576)       // xb [T,H] bf16 = 8,388,608
#define OFF_WGT   ((size_t)8669184)      // wgT [E][I][H] bf16
#define OFF_WUT   ((size_t)142886912)    // wuT [E][I][H] bf16
#define OFF_WSGT  ((size_t)277104640)    // wsgT [IS][H] bf16
#define OFF_WSUT  ((size_t)285493248)    // wsuT [IS][H] bf16
#define OFF_WDT   ((size_t)293881856)    // wdT [H][K_TOT] bf16
#define OFF_ACT   ((size_t)436488192)    // act [24576][1024] bf16 = 50,331,648

__device__ __forceinline__ unsigned short f2bf(float f) {
  unsigned int u = __float_as_uint(f);
  u += 0x7fffu + ((u >> 16) & 1u);   // round-to-nearest-even
  return (unsigned short)(u >> 16);
}

__device__ __forceinline__ void gld16(const void* g, void* l) {
  __builtin_amdgcn_global_load_lds(
      (const __attribute__((address_space(1))) unsigned int*)g,
      (__attribute__((address_space(3))) unsigned int*)l, 16, 0, 0);
}

// ---------------------------------------------------------------------------
// Router: scores = sigmoid(x @ gw^T); top-8; renorm; *2.5 -> pair lists.
// Also emits xb (bf16 x) from the row already staged in LDS (cvt fused).
// ---------------------------------------------------------------------------
__global__ __launch_bounds__(256) void router_kernel(
    const float* __restrict__ x, const float* __restrict__ gw,
    int* __restrict__ cnt, unsigned int* __restrict__ pairs,
    unsigned short* __restrict__ xb)
{
  const int t = blockIdx.x;
  __shared__ float xs[H_DIM];
  __shared__ float sc[E_NUM];
  const float4* xr = (const float4*)(x + (long)t * H_DIM);
  for (int i = threadIdx.x; i < H_DIM / 4; i += 256) ((float4*)xs)[i] = xr[i];
  __syncthreads();
  // fused x -> bf16 (8 elems/thread)
  {
    const int i0 = threadIdx.x * 8;
    ushort4 o1, o2;
    o1.x = f2bf(xs[i0 + 0]); o1.y = f2bf(xs[i0 + 1]);
    o1.z = f2bf(xs[i0 + 2]); o1.w = f2bf(xs[i0 + 3]);
    o2.x = f2bf(xs[i0 + 4]); o2.y = f2bf(xs[i0 + 5]);
    o2.z = f2bf(xs[i0 + 6]); o2.w = f2bf(xs[i0 + 7]);
    *(ushort4*)(xb + (long)t * H_DIM + i0) = o1;
    *(ushort4*)(xb + (long)t * H_DIM + i0 + 4) = o2;
  }
  const int e = threadIdx.x >> 3, p = threadIdx.x & 7;
  const float4* ga = (const float4*)(gw + (long)e * H_DIM);
  const float4* xa = (const float4*)xs;
  float s = 0.f;
  #pragma unroll 4
  for (int i = p * 64; i < p * 64 + 64; ++i) {
    float4 a = ga[i], b = xa[i];
    s += a.x * b.x + a.y * b.y + a.z * b.z + a.w * b.w;
  }
  s += __shfl_down(s, 4, 8);
  s += __shfl_down(s, 2, 8);
  s += __shfl_down(s, 1, 8);
  if (p == 0) sc[e] = 1.f / (1.f + expf(-s));
  __syncthreads();
  if (threadIdx.x == 0) {
    float v[E_NUM];
    #pragma unroll
    for (int i = 0; i < E_NUM; ++i) v[i] = sc[i];
    unsigned mask = 0; float sum = 0.f;
    int sel[8]; float wv[8];
    for (int k = 0; k < 8; ++k) {
      float best = -1.f; int bi = 0;
      for (int i = 0; i < E_NUM; ++i)
        if (!((mask >> i) & 1u) && v[i] > best) { best = v[i]; bi = i; }
      mask |= 1u << bi; sel[k] = bi; wv[k] = best; sum += best;
    }
    const float scale = 2.5f / (sum + 1e-20f);
    for (int k = 0; k < 8; ++k) {
      const int slot = atomicAdd(&cnt[sel[k]], 1);
      if (slot < SLOT_CAP) {
        const unsigned int w16 = (unsigned int)f2bf(wv[k] * scale);
        pairs[sel[k] * SLOT_CAP + slot] = (w16 << 16) | (unsigned int)t;
      }
    }
  }
}

// ---------------------------------------------------------------------------
// Build tile lists + per-expert act bases; fill shared pseudo-expert pairs.
// ---------------------------------------------------------------------------
__global__ __launch_bounds__(256) void build_tiles_kernel(
    int* __restrict__ cnt, int* __restrict__ base,
    unsigned int* __restrict__ tgu, int* __restrict__ ntgu,
    unsigned int* __restrict__ tdn, int* __restrict__ ntdn,
    unsigned int* __restrict__ pairs)
{
  const int t = threadIdx.x;
  for (int s = t; s < T_TOK; s += 256) {
    const unsigned int pv = (0x3F80u << 16) | (unsigned int)s;  // w=1.0 bf16
    pairs[32 * SLOT_CAP + s] = pv;
    pairs[33 * SLOT_CAP + s] = pv;
  }
  if (t == 0) {
    cnt[32] = T_TOK; cnt[33] = T_TOK;
    int b = 0, ngu = 0, ndn = 0;
    for (int e = 0; e < NE_ALL; ++e) {
      const int c = (e < 32) ? cnt[e] : T_TOK;
      base[e] = b;
      for (int m0 = 0; m0 < c; m0 += 128) {
        tgu[ngu++] = ((unsigned int)e << 16) | (unsigned int)m0;
        if (e < 33) tdn[ndn++] = ((unsigned int)e << 16) | (unsigned int)m0;
      }
      b += (c + 127) & ~127;
    }
    *ntgu = ngu; *ntdn = ndn;
  }
}

// ---------------------------------------------------------------------------
// Transpose+cvt, 64(c) x 256(r) tiles — measured at its mixed-stream limit
// (~274us fused, 3 structural variants identical); now split into TWO
// launches (gate/up weights vs down weights) for per-GEMM counter visibility.
// ---------------------------------------------------------------------------
struct TDescTable {
  const float* in[6];
  unsigned short* out[6];
  int C[6];
  int ldout[6];
  long in_bs[6];
  long out_bs[6];
  int nbx[6];
  int nbxy[6];
  int start[7];
};

__global__ __launch_bounds__(256) void transpose_fused(TDescTable td)
{
  const int bid = blockIdx.x;
  int i = 0;
  while (i < 5 && bid >= td.start[i + 1]) ++i;
  const int local = bid - td.start[i];
  const int bz = local / td.nbxy[i];
  const int rem = local % td.nbxy[i];
  const int by = rem / td.nbx[i];
  const int bx = rem % td.nbx[i];
  const float* in = td.in[i] + (long)bz * td.in_bs[i];
  unsigned short* out = td.out[i] + (long)bz * td.out_bs[i];
  const int C = td.C[i], ldout = td.ldout[i];

  __shared__ unsigned short tile[64][258];
  const int c0 = bx * 64;
  const int r0 = by * 256;
  const int t = threadIdx.x;
  const int rl0 = t >> 4;          // 0..15
  const int cl0 = (t & 15) * 4;    // 0..60

  float4 v[16];
  #pragma unroll
  for (int p = 0; p < 16; ++p) {
    const int rl = p * 16 + rl0;
    v[p] = *(const float4*)(in + (long)(r0 + rl) * C + c0 + cl0);
  }
  __builtin_amdgcn_sched_barrier(0);
  #pragma unroll
  for (int p = 0; p < 16; ++p) {
    const int rl = p * 16 + rl0;
    tile[cl0 + 0][rl] = f2bf(v[p].x);
    tile[cl0 + 1][rl] = f2bf(v[p].y);
    tile[cl0 + 2][rl] = f2bf(v[p].z);
    tile[cl0 + 3][rl] = f2bf(v[p].w);
  }
  __syncthreads();
  const int cw = t >> 5;           // 0..7
  const int rw = (t & 31) * 8;     // 0..248
  #pragma unroll
  for (int q = 0; q < 8; ++q) {
    const int cl = q * 8 + cw;
    const char* src = (const char*)&tile[cl][rw];  // 4B-aligned
    uint4 o;
    o.x = *(const unsigned int*)(src + 0);
    o.y = *(const unsigned int*)(src + 4);
    o.z = *(const unsigned int*)(src + 8);
    o.w = *(const unsigned int*)(src + 12);
    *(uint4*)(out + (long)(c0 + cl) * ldout + r0 + rw) = o;
  }
}

// ---------------------------------------------------------------------------
// Unified gate+up GEMM over GU tile list. 256 thr, 4 waves (2Mx2N), wave tile
// 64x32, block 128x64, single-buffered 32KB LDS (5 blocks/CU), 2-barrier
// K-loop, XOR-swizzled LDS, gathered A rows, setprio around MFMA.
// ---------------------------------------------------------------------------
__global__ __launch_bounds__(256) void gate_up_moe_kernel(
    const unsigned short* __restrict__ xb,
    const unsigned short* __restrict__ bgT,
    const unsigned short* __restrict__ buT,
    const unsigned short* __restrict__ sgT,
    const unsigned short* __restrict__ suT,
    const int* __restrict__ cnt,
    const int* __restrict__ base,
    const unsigned int* __restrict__ pairs,
    const unsigned int* __restrict__ tiles,
    const int* __restrict__ ntp,
    unsigned short* __restrict__ act)
{
  const int ti = blockIdx.y;
  if (ti >= *ntp) return;
  const unsigned int tile = tiles[ti];
  const int e  = (int)(tile >> 16);
  const int m0 = (int)(tile & 0xFFFFu);
  const int cnte = cnt[e];
  const int be = base[e];
  const int n0 = blockIdx.x * 64;
  const long panel = (long)I_DIM * H_DIM;
  const unsigned short* Bg =
      ((e < 32) ? bgT + e * panel : sgT + (e - 32) * panel) + (long)n0 * H_DIM;
  const unsigned short* Bu =
      ((e < 32) ? buT + e * panel : suT + (e - 32) * panel) + (long)n0 * H_DIM;

  __shared__ unsigned short sA[128 * 64];
  __shared__ unsigned short sBg[64 * 64];
  __shared__ unsigned short sBu[64 * 64];

  const int tid = threadIdx.x;
  const int lane = tid & 63;
  const int wid = tid >> 6;
  const int wm = wid >> 1, wn = wid & 1;
  const int l15 = lane & 15;
  const int lk  = (lane >> 4) * 8;
  const int srow = tid >> 3;                       // 0..31
  const int scol = (tid & 7) * 8;
  const int scolsw = (((tid & 7) ^ (srow & 7))) * 8;
  const int ksw = (l15 & 7) << 3;

  const unsigned short* asrc[4];
  #pragma unroll
  for (int r = 0; r < 4; ++r) {
    const int slot = m0 + r * 32 + srow;
    const unsigned int pr = (slot < cnte) ? pairs[e * SLOT_CAP + slot] : 0u;
    asrc[r] = xb + (long)(pr & 0xFFFFu) * H_DIM + scolsw;
  }

  const f32x4 fz = {0.f, 0.f, 0.f, 0.f};
  f32x4 accg[4][2], accu[4][2];
  #pragma unroll
  for (int i = 0; i < 4; ++i)
    #pragma unroll
    for (int j = 0; j < 2; ++j) { accg[i][j] = fz; accu[i][j] = fz; }

  for (int k0 = 0; k0 < H_DIM; k0 += 64) {
    #pragma unroll
    for (int r = 0; r < 4; ++r)
      gld16(asrc[r] + k0, sA + (r * 32 + srow) * 64 + scol);
    #pragma unroll
    for (int r = 0; r < 2; ++r) {
      gld16(Bg + (long)(r * 32 + srow) * H_DIM + k0 + scolsw,
            sBg + (r * 32 + srow) * 64 + scol);
      gld16(Bu + (long)(r * 32 + srow) * H_DIM + k0 + scolsw,
            sBu + (r * 32 + srow) * 64 + scol);
    }
    __syncthreads();
    __builtin_amdgcn_s_setprio(1);
    #pragma unroll
    for (int kk = 0; kk < 2; ++kk) {
      const int ko = kk * 32 + lk;
      bf16x8 a[4], g[2], u[2];
      #pragma unroll
      for (int mi = 0; mi < 4; ++mi)
        a[mi] = *(const bf16x8*)(sA + (wm * 64 + mi * 16 + l15) * 64 + (ko ^ ksw));
      #pragma unroll
      for (int ni = 0; ni < 2; ++ni) {
        g[ni] = *(const bf16x8*)(sBg + (wn * 32 + ni * 16 + l15) * 64 + (ko ^ ksw));
        u[ni] = *(const bf16x8*)(sBu + (wn * 32 + ni * 16 + l15) * 64 + (ko ^ ksw));
      }
      #pragma unroll
      for (int mi = 0; mi < 4; ++mi)
        #pragma unroll
        for (int ni = 0; ni < 2; ++ni) {
          accg[mi][ni] = __builtin_amdgcn_mfma_f32_16x16x32_bf16(a[mi], g[ni], accg[mi][ni], 0, 0, 0);
          accu[mi][ni] = __builtin_amdgcn_mfma_f32_16x16x32_bf16(a[mi], u[ni], accu[mi][ni], 0, 0, 0);
        }
    }
    __builtin_amdgcn_s_setprio(0);
    __syncthreads();
  }

  const int colb = n0 + wn * 32;
  #pragma unroll
  for (int mi = 0; mi < 4; ++mi) {
    #pragma unroll
    for (int r = 0; r < 4; ++r) {
      const int slot = m0 + wm * 64 + mi * 16 + (lane >> 4) * 4 + r;
      if (slot < cnte) {
        const unsigned int pr = pairs[e * SLOT_CAP + slot];
        const float w = __uint_as_float(pr & 0xFFFF0000u);
        #pragma unroll
        for (int ni = 0; ni < 2; ++ni) {
          const float gv = accg[mi][ni][r];
          const float uv = accu[mi][ni][r];
          const float sv = (gv / (1.f + expf(-gv))) * uv * w;
          act[((long)(be + slot)) * I_DIM + colb + ni * 16 + l15] = f2bf(sv);
        }
      }
    }
  }
}

// ---------------------------------------------------------------------------
// Unified down GEMM over DN tile list. 256 thr, 4 waves (2Mx2N), wave tile
// 64x64, block 128(M)x128(N), single-buf 32KB LDS, 2-barrier loop.
// e=32 runs K=2048 spanning both shared act panels. atomicAdd onto zeroed out.
// ---------------------------------------------------------------------------
__global__ __launch_bounds__(256) void down_moe_kernel(
    const unsigned short* __restrict__ act,
    const unsigned short* __restrict__ wdT,
    const int* __restrict__ cnt,
    const int* __restrict__ base,
    const unsigned int* __restrict__ pairs,
    const unsigned int* __restrict__ tiles,
    const int* __restrict__ ntp,
    float* __restrict__ out)
{
  const int ti = blockIdx.y;
  if (ti >= *ntp) return;
  const unsigned int tile = tiles[ti];
  const int e  = (int)(tile >> 16);
  const int m0 = (int)(tile & 0xFFFFu);
  const int cnte = cnt[e];
  const int n0 = blockIdx.x * 128;
  const unsigned short* A = act + ((long)base[e] + m0) * I_DIM;
  const unsigned short* B = wdT + (long)n0 * K_TOT + (long)e * I_DIM;
  const int nk = (e == 32) ? 32 : 16;   // K-steps of 64

  __shared__ unsigned short sA[128 * 64];
  __shared__ unsigned short sB[128 * 64];

  const int tid = threadIdx.x;
  const int lane = tid & 63;
  const int wid = tid >> 6;
  const int wm = wid >> 1, wn = wid & 1;
  const int l15 = lane & 15;
  const int lk  = (lane >> 4) * 8;
  const int srow = tid >> 3;                       // 0..31
  const int scol = (tid & 7) * 8;
  const int scolsw = (((tid & 7) ^ (srow & 7))) * 8;
  const int ksw = (l15 & 7) << 3;

  const f32x4 fz = {0.f, 0.f, 0.f, 0.f};
  f32x4 acc[4][4];
  #pragma unroll
  for (int i = 0; i < 4; ++i)
    #pragma unroll
    for (int j = 0; j < 4; ++j) acc[i][j] = fz;

  for (int t = 0; t < nk; ++t) {
    const int k0 = t * 64;
    const long koff = (long)(k0 & 1023) + (long)(k0 >> 10) * (2048L * 1024L);
    #pragma unroll
    for (int r = 0; r < 4; ++r)
      gld16(A + (long)(r * 32 + srow) * I_DIM + koff + scolsw,
            sA + (r * 32 + srow) * 64 + scol);
    #pragma unroll
    for (int r = 0; r < 4; ++r)
      gld16(B + (long)(r * 32 + srow) * K_TOT + k0 + scolsw,
            sB + (r * 32 + srow) * 64 + scol);
    __syncthreads();
    __builtin_amdgcn_s_setprio(1);
    #pragma unroll
    for (int kk = 0; kk < 2; ++kk) {
      const int ko = kk * 32 + lk;
      bf16x8 a[4], b[4];
      #pragma unroll
      for (int mi = 0; mi < 4; ++mi)
        a[mi] = *(const bf16x8*)(sA + (wm * 64 + mi * 16 + l15) * 64 + (ko ^ ksw));
      #pragma unroll
      for (int ni = 0; ni < 4; ++ni)
        b[ni] = *(const bf16x8*)(sB + (wn * 64 + ni * 16 + l15) * 64 + (ko ^ ksw));
      #pragma unroll
      for (int mi = 0; mi < 4; ++mi)
        #pragma unroll
        for (int ni = 0; ni < 4; ++ni)
          acc[mi][ni] = __builtin_amdgcn_mfma_f32_16x16x32_bf16(a[mi], b[ni], acc[mi][ni], 0, 0, 0);
    }
    __builtin_amdgcn_s_setprio(0);
    __syncthreads();
  }

  #pragma unroll
  for (int mi = 0; mi < 4; ++mi) {
    #pragma unroll
    for (int r = 0; r < 4; ++r) {
      const int slot = m0 + wm * 64 + mi * 16 + (lane >> 4) * 4 + r;
      if (slot < cnte) {
        const int tok = (int)(pairs[e * SLOT_CAP + slot] & 0xFFFFu);
        #pragma unroll
        for (int ni = 0; ni < 4; ++ni)
          atomicAdd(out + (long)tok * H_DIM + n0 + wn * 64 + ni * 16 + l15,
                    acc[mi][ni][r]);
      }
    }
  }
}

// ---------------------------------------------------------------------------
extern "C" void kernel_launch(void* const* d_in, const int* in_sizes, int n_in,
                              void* d_out, int out_size, void* d_ws, size_t ws_size,
                              hipStream_t stream) {
  (void)in_sizes; (void)n_in; (void)ws_size;
  const float* x   = (const float*)d_in[0];
  const float* gw  = (const float*)d_in[1];
  const float* wg  = (const float*)d_in[2];
  const float* wu  = (const float*)d_in[3];
  const float* wd  = (const float*)d_in[4];
  const float* wsg = (const float*)d_in[5];
  const float* wsu = (const float*)d_in[6];
  const float* wsd = (const float*)d_in[7];
  float* out = (float*)d_out;
  char* ws = (char*)d_ws;

  int*            cnt   = (int*)(ws + OFF_CNT);
  int*            ntgu  = (int*)(ws + OFF_NTGU);
  int*            ntdn  = (int*)(ws + OFF_NTDN);
  int*            basep = (int*)(ws + OFF_BASE);
  unsigned int*   tgu   = (unsigned int*)(ws + OFF_TGU);
  unsigned int*   tdn   = (unsigned int*)(ws + OFF_TDN);
  unsigned int*   pairs = (unsigned int*)(ws + OFF_PAIRS);
  unsigned short* xb    = (unsigned short*)(ws + OFF_XB);
  unsigned short* wgT   = (unsigned short*)(ws + OFF_WGT);
  unsigned short* wuT   = (unsigned short*)(ws + OFF_WUT);
  unsigned short* wsgT  = (unsigned short*)(ws + OFF_WSGT);
  unsigned short* wsuT  = (unsigned short*)(ws + OFF_WSUT);
  unsigned short* wdT   = (unsigned short*)(ws + OFF_WDT);
  unsigned short* actb  = (unsigned short*)(ws + OFF_ACT);

  hipMemsetAsync(ws + OFF_CNT, 0, 256, stream);           // cnt + nt
  hipMemsetAsync(out, 0, (size_t)out_size * sizeof(float), stream);

  // router (emits pair lists AND xb via fused cvt)
  router_kernel<<<T_TOK, 256, 0, stream>>>(x, gw, cnt, pairs, xb);
  build_tiles_kernel<<<1, 256, 0, stream>>>(cnt, basep, tgu, ntgu, tdn, ntdn,
                                            pairs);

  // transpose A: gate/up weights (wg, wu, wsg, wsu)
  TDescTable ta;
  ta.in[0] = wg;  ta.out[0] = wgT;  ta.C[0] = I_DIM;  ta.ldout[0] = H_DIM;
  ta.in_bs[0] = (long)H_DIM * I_DIM; ta.out_bs[0] = (long)I_DIM * H_DIM;
  ta.nbx[0] = I_DIM / 64; ta.nbxy[0] = (I_DIM / 64) * (H_DIM / 256);
  ta.in[1] = wu;  ta.out[1] = wuT;  ta.C[1] = I_DIM;  ta.ldout[1] = H_DIM;
  ta.in_bs[1] = (long)H_DIM * I_DIM; ta.out_bs[1] = (long)I_DIM * H_DIM;
  ta.nbx[1] = I_DIM / 64; ta.nbxy[1] = (I_DIM / 64) * (H_DIM / 256);
  ta.in[2] = wsg; ta.out[2] = wsgT; ta.C[2] = IS_DIM; ta.ldout[2] = H_DIM;
  ta.in_bs[2] = 0; ta.out_bs[2] = 0;
  ta.nbx[2] = IS_DIM / 64; ta.nbxy[2] = (IS_DIM / 64) * (H_DIM / 256);
  ta.in[3] = wsu; ta.out[3] = wsuT; ta.C[3] = IS_DIM; ta.ldout[3] = H_DIM;
  ta.in_bs[3] = 0; ta.out_bs[3] = 0;
  ta.nbx[3] = IS_DIM / 64; ta.nbxy[3] = (IS_DIM / 64) * (H_DIM / 256);
  ta.in[4] = wsu; ta.out[4] = wsuT; ta.C[4] = IS_DIM; ta.ldout[4] = H_DIM;
  ta.in_bs[4] = 0; ta.out_bs[4] = 0; ta.nbx[4] = 1; ta.nbxy[4] = 1;
  ta.in[5] = ta.in[4]; ta.out[5] = ta.out[4]; ta.C[5] = ta.C[4];
  ta.ldout[5] = ta.ldout[4]; ta.in_bs[5] = 0; ta.out_bs[5] = 0;
  ta.nbx[5] = 1; ta.nbxy[5] = 1;
  ta.start[0] = 0;
  ta.start[1] = ta.start[0] + ta.nbxy[0] * E_NUM;
  ta.start[2] = ta.start[1] + ta.nbxy[1] * E_NUM;
  ta.start[3] = ta.start[2] + ta.nbxy[2];
  ta.start[4] = ta.start[3] + ta.nbxy[3];
  ta.start[5] = ta.start[4];          // empty
  ta.start[6] = ta.start[5];          // empty
  transpose_fused<<<ta.start[6] == ta.start[4] ? ta.start[4] : ta.start[6],
                    256, 0, stream>>>(ta);

  // unified gate+up (routed + shared pseudo-experts) -> compact act
  gate_up_moe_kernel<<<dim3(16, GU_TILES), 256, 0, stream>>>(
      xb, wgT, wuT, wsgT, wsuT, cnt, basep, pairs, tgu, ntgu, actb);

  // transpose B: down weights (wd, wsd)
  TDescTable tb;
  tb.in[0] = wd;  tb.out[0] = wdT;  tb.C[0] = H_DIM;  tb.ldout[0] = K_TOT;
  tb.in_bs[0] = (long)I_DIM * H_DIM; tb.out_bs[0] = (long)I_DIM;
  tb.nbx[0] = H_DIM / 64; tb.nbxy[0] = (H_DIM / 64) * (I_DIM / 256);
  tb.in[1] = wsd; tb.out[1] = wdT + E_NUM * I_DIM; tb.C[1] = H_DIM;
  tb.ldout[1] = K_TOT; tb.in_bs[1] = 0; tb.out_bs[1] = 0;
  tb.nbx[1] = H_DIM / 64; tb.nbxy[1] = (H_DIM / 64) * (IS_DIM / 256);
  for (int i = 2; i < 6; ++i) {
    tb.in[i] = tb.in[1]; tb.out[i] = tb.out[1]; tb.C[i] = tb.C[1];
    tb.ldout[i] = tb.ldout[1]; tb.in_bs[i] = 0; tb.out_bs[i] = 0;
    tb.nbx[i] = 1; tb.nbxy[i] = 1;
  }
  tb.start[0] = 0;
  tb.start[1] = tb.start[0] + tb.nbxy[0] * E_NUM;
  tb.start[2] = tb.start[1] + tb.nbxy[1];
  tb.start[3] = tb.start[2];
  tb.start[4] = tb.start[2];
  tb.start[5] = tb.start[2];
  tb.start[6] = tb.start[2];
  transpose_fused<<<tb.start[6], 256, 0, stream>>>(tb);

  // unified down (routed K=1024, shared K=2048) -> atomicAdd onto zeroed out
  down_moe_kernel<<<dim3(16, DN_TILES), 256, 0, stream>>>(
      actb, wdT, cnt, basep, pairs, tdn, ntdn, out);
}

// Round 12
// 753.369 us; speedup vs baseline: 1.2436x; 1.1058x over previous
//
#include <hip/hip_runtime.h>

// Problem dims (fixed by the reference)
#define T_TOK 2048      // B*S tokens
#define H_DIM 2048
#define E_NUM 32
#define I_DIM 1024
#define IS_DIM 2048
#define K_TOT (E_NUM * I_DIM + IS_DIM)   // 34816
#define SLOT_CAP 2048
#define NE_ALL 34        // 32 routed + 2 shared pseudo-experts
#define GU_TILES 192     // <=160 routed + 32 shared
#define DN_TILES 176     // <=160 routed + 16 shared (K=2048)
#define ACT_SLOTS 24576  // sum pad128(cnt_e) (<=20448) + 4096 shared

typedef __bf16 bf16x8 __attribute__((ext_vector_type(8)));
typedef float  f32x4  __attribute__((ext_vector_type(4)));
static_assert(sizeof(bf16x8) == 16, "bf16x8 must be 16B");

// Workspace layout (bytes). Total = 486,885,376.
// po [ACT_SLOTS][H] bf16 (100.7 MB) ALIASES wgT (dead after gate_up).
#define OFF_CNT   ((size_t)0)            // cnt[34] int
#define OFF_NTGU  ((size_t)192)
#define OFF_NTDN  ((size_t)196)
#define OFF_BASE  ((size_t)256)          // base[34] int
#define OFF_TGU   ((size_t)512)          // tilesGU[192] uint
#define OFF_TDN   ((size_t)1280)         // tilesDN[176] uint
#define OFF_PAIRS ((size_t)2048)         // pairs[34][2048] uint = 278,528
#define OFF_XB    ((size_t)280576)       // xb [T,H] bf16 = 8,388,608
#define OFF_WGT   ((size_t)8669184)      // wgT [E][I][H] bf16 (po aliases)
#define OFF_PO    OFF_WGT
#define OFF_WUT   ((size_t)142886912)    // wuT [E][I][H] bf16
#define OFF_WSGT  ((size_t)277104640)    // wsgT [IS][H] bf16
#define OFF_WSUT  ((size_t)285493248)    // wsuT [IS][H] bf16
#define OFF_WDT   ((size_t)293881856)    // wdT [H][K_TOT] bf16
#define OFF_ACT   ((size_t)436488192)    // act [24576][1024] bf16 = 50,331,648
#define OFF_TSLOT ((size_t)486819840)    // tslot[T][8] uint = 65,536

__device__ __forceinline__ unsigned short f2bf(float f) {
  unsigned int u = __float_as_uint(f);
  u += 0x7fffu + ((u >> 16) & 1u);   // round-to-nearest-even
  return (unsigned short)(u >> 16);
}

__device__ __forceinline__ void gld16(const void* g, void* l) {
  __builtin_amdgcn_global_load_lds(
      (const __attribute__((address_space(1))) unsigned int*)g,
      (__attribute__((address_space(3))) unsigned int*)l, 16, 0, 0);
}

// ---------------------------------------------------------------------------
// Router: scores = sigmoid(x @ gw^T); top-8; renorm; *2.5 -> pair lists +
// per-token (e,slot) list (tslot) + fused x->bf16 (xb).
// ---------------------------------------------------------------------------
__global__ __launch_bounds__(256) void router_kernel(
    const float* __restrict__ x, const float* __restrict__ gw,
    int* __restrict__ cnt, unsigned int* __restrict__ pairs,
    unsigned int* __restrict__ tslot, unsigned short* __restrict__ xb)
{
  const int t = blockIdx.x;
  __shared__ float xs[H_DIM];
  __shared__ float sc[E_NUM];
  const float4* xr = (const float4*)(x + (long)t * H_DIM);
  for (int i = threadIdx.x; i < H_DIM / 4; i += 256) ((float4*)xs)[i] = xr[i];
  __syncthreads();
  // fused x -> bf16 (8 elems/thread)
  {
    const int i0 = threadIdx.x * 8;
    ushort4 o1, o2;
    o1.x = f2bf(xs[i0 + 0]); o1.y = f2bf(xs[i0 + 1]);
    o1.z = f2bf(xs[i0 + 2]); o1.w = f2bf(xs[i0 + 3]);
    o2.x = f2bf(xs[i0 + 4]); o2.y = f2bf(xs[i0 + 5]);
    o2.z = f2bf(xs[i0 + 6]); o2.w = f2bf(xs[i0 + 7]);
    *(ushort4*)(xb + (long)t * H_DIM + i0) = o1;
    *(ushort4*)(xb + (long)t * H_DIM + i0 + 4) = o2;
  }
  const int e = threadIdx.x >> 3, p = threadIdx.x & 7;
  const float4* ga = (const float4*)(gw + (long)e * H_DIM);
  const float4* xa = (const float4*)xs;
  float s = 0.f;
  #pragma unroll 4
  for (int i = p * 64; i < p * 64 + 64; ++i) {
    float4 a = ga[i], b = xa[i];
    s += a.x * b.x + a.y * b.y + a.z * b.z + a.w * b.w;
  }
  s += __shfl_down(s, 4, 8);
  s += __shfl_down(s, 2, 8);
  s += __shfl_down(s, 1, 8);
  if (p == 0) sc[e] = 1.f / (1.f + expf(-s));
  __syncthreads();
  if (threadIdx.x == 0) {
    float v[E_NUM];
    #pragma unroll
    for (int i = 0; i < E_NUM; ++i) v[i] = sc[i];
    unsigned mask = 0; float sum = 0.f;
    int sel[8]; float wv[8];
    for (int k = 0; k < 8; ++k) {
      float best = -1.f; int bi = 0;
      for (int i = 0; i < E_NUM; ++i)
        if (!((mask >> i) & 1u) && v[i] > best) { best = v[i]; bi = i; }
      mask |= 1u << bi; sel[k] = bi; wv[k] = best; sum += best;
    }
    const float scale = 2.5f / (sum + 1e-20f);
    for (int k = 0; k < 8; ++k) {
      const int slot = atomicAdd(&cnt[sel[k]], 1);
      if (slot < SLOT_CAP) {
        const unsigned int w16 = (unsigned int)f2bf(wv[k] * scale);
        pairs[sel[k] * SLOT_CAP + slot] = (w16 << 16) | (unsigned int)t;
        tslot[t * 8 + k] = ((unsigned int)sel[k] << 16) | (unsigned int)slot;
      }
    }
  }
}

// ---------------------------------------------------------------------------
// Build tile lists + per-expert act bases; fill shared pseudo-expert pairs.
// ---------------------------------------------------------------------------
__global__ __launch_bounds__(256) void build_tiles_kernel(
    int* __restrict__ cnt, int* __restrict__ base,
    unsigned int* __restrict__ tgu, int* __restrict__ ntgu,
    unsigned int* __restrict__ tdn, int* __restrict__ ntdn,
    unsigned int* __restrict__ pairs)
{
  const int t = threadIdx.x;
  for (int s = t; s < T_TOK; s += 256) {
    const unsigned int pv = (0x3F80u << 16) | (unsigned int)s;  // w=1.0 bf16
    pairs[32 * SLOT_CAP + s] = pv;
    pairs[33 * SLOT_CAP + s] = pv;
  }
  if (t == 0) {
    cnt[32] = T_TOK; cnt[33] = T_TOK;
    int b = 0, ngu = 0, ndn = 0;
    for (int e = 0; e < NE_ALL; ++e) {
      const int c = (e < 32) ? cnt[e] : T_TOK;
      base[e] = b;
      for (int m0 = 0; m0 < c; m0 += 128) {
        tgu[ngu++] = ((unsigned int)e << 16) | (unsigned int)m0;
        if (e < 33) tdn[ndn++] = ((unsigned int)e << 16) | (unsigned int)m0;
      }
      b += (c + 127) & ~127;
    }
    *ntgu = ngu; *ntdn = ndn;
  }
}

// ---------------------------------------------------------------------------
// Transpose+cvt, 64(c) x 256(r) tiles — at its mixed-stream limit; two
// launches (gate/up weights, down weights) for counter visibility.
// ---------------------------------------------------------------------------
struct TDescTable {
  const float* in[6];
  unsigned short* out[6];
  int C[6];
  int ldout[6];
  long in_bs[6];
  long out_bs[6];
  int nbx[6];
  int nbxy[6];
  int start[7];
};

__global__ __launch_bounds__(256) void transpose_fused(TDescTable td)
{
  const int bid = blockIdx.x;
  int i = 0;
  while (i < 5 && bid >= td.start[i + 1]) ++i;
  const int local = bid - td.start[i];
  const int bz = local / td.nbxy[i];
  const int rem = local % td.nbxy[i];
  const int by = rem / td.nbx[i];
  const int bx = rem % td.nbx[i];
  const float* in = td.in[i] + (long)bz * td.in_bs[i];
  unsigned short* out = td.out[i] + (long)bz * td.out_bs[i];
  const int C = td.C[i], ldout = td.ldout[i];

  __shared__ unsigned short tile[64][258];
  const int c0 = bx * 64;
  const int r0 = by * 256;
  const int t = threadIdx.x;
  const int rl0 = t >> 4;          // 0..15
  const int cl0 = (t & 15) * 4;    // 0..60

  float4 v[16];
  #pragma unroll
  for (int p = 0; p < 16; ++p) {
    const int rl = p * 16 + rl0;
    v[p] = *(const float4*)(in + (long)(r0 + rl) * C + c0 + cl0);
  }
  __builtin_amdgcn_sched_barrier(0);
  #pragma unroll
  for (int p = 0; p < 16; ++p) {
    const int rl = p * 16 + rl0;
    tile[cl0 + 0][rl] = f2bf(v[p].x);
    tile[cl0 + 1][rl] = f2bf(v[p].y);
    tile[cl0 + 2][rl] = f2bf(v[p].z);
    tile[cl0 + 3][rl] = f2bf(v[p].w);
  }
  __syncthreads();
  const int cw = t >> 5;           // 0..7
  const int rw = (t & 31) * 8;     // 0..248
  #pragma unroll
  for (int q = 0; q < 8; ++q) {
    const int cl = q * 8 + cw;
    const char* src = (const char*)&tile[cl][rw];  // 4B-aligned
    uint4 o;
    o.x = *(const unsigned int*)(src + 0);
    o.y = *(const unsigned int*)(src + 4);
    o.z = *(const unsigned int*)(src + 8);
    o.w = *(const unsigned int*)(src + 12);
    *(uint4*)(out + (long)(c0 + cl) * ldout + r0 + rw) = o;
  }
}

// ---------------------------------------------------------------------------
// Unified gate+up GEMM over GU tile list. 256 thr, 4 waves (2Mx2N), wave tile
// 64x32, block 128x64, single-buffered 32KB LDS, 2-barrier K-loop,
// XOR-swizzled LDS, gathered A rows, setprio around MFMA.
// ---------------------------------------------------------------------------
__global__ __launch_bounds__(256) void gate_up_moe_kernel(
    const unsigned short* __restrict__ xb,
    const unsigned short* __restrict__ bgT,
    const unsigned short* __restrict__ buT,
    const unsigned short* __restrict__ sgT,
    const unsigned short* __restrict__ suT,
    const int* __restrict__ cnt,
    const int* __restrict__ base,
    const unsigned int* __restrict__ pairs,
    const unsigned int* __restrict__ tiles,
    const int* __restrict__ ntp,
    unsigned short* __restrict__ act)
{
  const int ti = blockIdx.y;
  if (ti >= *ntp) return;
  const unsigned int tile = tiles[ti];
  const int e  = (int)(tile >> 16);
  const int m0 = (int)(tile & 0xFFFFu);
  const int cnte = cnt[e];
  const int be = base[e];
  const int n0 = blockIdx.x * 64;
  const long panel = (long)I_DIM * H_DIM;
  const unsigned short* Bg =
      ((e < 32) ? bgT + e * panel : sgT + (e - 32) * panel) + (long)n0 * H_DIM;
  const unsigned short* Bu =
      ((e < 32) ? buT + e * panel : suT + (e - 32) * panel) + (long)n0 * H_DIM;

  __shared__ unsigned short sA[128 * 64];
  __shared__ unsigned short sBg[64 * 64];
  __shared__ unsigned short sBu[64 * 64];

  const int tid = threadIdx.x;
  const int lane = tid & 63;
  const int wid = tid >> 6;
  const int wm = wid >> 1, wn = wid & 1;
  const int l15 = lane & 15;
  const int lk  = (lane >> 4) * 8;
  const int srow = tid >> 3;                       // 0..31
  const int scol = (tid & 7) * 8;
  const int scolsw = (((tid & 7) ^ (srow & 7))) * 8;
  const int ksw = (l15 & 7) << 3;

  const unsigned short* asrc[4];
  #pragma unroll
  for (int r = 0; r < 4; ++r) {
    const int slot = m0 + r * 32 + srow;
    const unsigned int pr = (slot < cnte) ? pairs[e * SLOT_CAP + slot] : 0u;
    asrc[r] = xb + (long)(pr & 0xFFFFu) * H_DIM + scolsw;
  }

  const f32x4 fz = {0.f, 0.f, 0.f, 0.f};
  f32x4 accg[4][2], accu[4][2];
  #pragma unroll
  for (int i = 0; i < 4; ++i)
    #pragma unroll
    for (int j = 0; j < 2; ++j) { accg[i][j] = fz; accu[i][j] = fz; }

  for (int k0 = 0; k0 < H_DIM; k0 += 64) {
    #pragma unroll
    for (int r = 0; r < 4; ++r)
      gld16(asrc[r] + k0, sA + (r * 32 + srow) * 64 + scol);
    #pragma unroll
    for (int r = 0; r < 2; ++r) {
      gld16(Bg + (long)(r * 32 + srow) * H_DIM + k0 + scolsw,
            sBg + (r * 32 + srow) * 64 + scol);
      gld16(Bu + (long)(r * 32 + srow) * H_DIM + k0 + scolsw,
            sBu + (r * 32 + srow) * 64 + scol);
    }
    __syncthreads();
    __builtin_amdgcn_s_setprio(1);
    #pragma unroll
    for (int kk = 0; kk < 2; ++kk) {
      const int ko = kk * 32 + lk;
      bf16x8 a[4], g[2], u[2];
      #pragma unroll
      for (int mi = 0; mi < 4; ++mi)
        a[mi] = *(const bf16x8*)(sA + (wm * 64 + mi * 16 + l15) * 64 + (ko ^ ksw));
      #pragma unroll
      for (int ni = 0; ni < 2; ++ni) {
        g[ni] = *(const bf16x8*)(sBg + (wn * 32 + ni * 16 + l15) * 64 + (ko ^ ksw));
        u[ni] = *(const bf16x8*)(sBu + (wn * 32 + ni * 16 + l15) * 64 + (ko ^ ksw));
      }
      #pragma unroll
      for (int mi = 0; mi < 4; ++mi)
        #pragma unroll
        for (int ni = 0; ni < 2; ++ni) {
          accg[mi][ni] = __builtin_amdgcn_mfma_f32_16x16x32_bf16(a[mi], g[ni], accg[mi][ni], 0, 0, 0);
          accu[mi][ni] = __builtin_amdgcn_mfma_f32_16x16x32_bf16(a[mi], u[ni], accu[mi][ni], 0, 0, 0);
        }
    }
    __builtin_amdgcn_s_setprio(0);
    __syncthreads();
  }

  const int colb = n0 + wn * 32;
  #pragma unroll
  for (int mi = 0; mi < 4; ++mi) {
    #pragma unroll
    for (int r = 0; r < 4; ++r) {
      const int slot = m0 + wm * 64 + mi * 16 + (lane >> 4) * 4 + r;
      if (slot < cnte) {
        const unsigned int pr = pairs[e * SLOT_CAP + slot];
        const float w = __uint_as_float(pr & 0xFFFF0000u);
        #pragma unroll
        for (int ni = 0; ni < 2; ++ni) {
          const float gv = accg[mi][ni][r];
          const float uv = accu[mi][ni][r];
          const float sv = (gv / (1.f + expf(-gv))) * uv * w;
          act[((long)(be + slot)) * I_DIM + colb + ni * 16 + l15] = f2bf(sv);
        }
      }
    }
  }
}

// ---------------------------------------------------------------------------
// Unified down GEMM over DN tile list. 256 thr, 4 waves (2Mx2N), wave tile
// 64x64, block 128(M)x128(N), single-buf 32KB LDS, 2-barrier loop.
// e=32 runs K=2048 spanning both shared act panels. Writes per-slot partial
// rows po[base[e]+slot][H] as PLAIN bf16 stores (no atomics — the round-11
// profile showed 39M fp32 atomicAdds consumed ~95% of this kernel's time).
// ---------------------------------------------------------------------------
__global__ __launch_bounds__(256) void down_moe_kernel(
    const unsigned short* __restrict__ act,
    const unsigned short* __restrict__ wdT,
    const int* __restrict__ cnt,
    const int* __restrict__ base,
    const unsigned int* __restrict__ tiles,
    const int* __restrict__ ntp,
    unsigned short* __restrict__ po)
{
  const int ti = blockIdx.y;
  if (ti >= *ntp) return;
  const unsigned int tile = tiles[ti];
  const int e  = (int)(tile >> 16);
  const int m0 = (int)(tile & 0xFFFFu);
  const int cnte = cnt[e];
  const int be = base[e];
  const int n0 = blockIdx.x * 128;
  const unsigned short* A = act + ((long)be + m0) * I_DIM;
  const unsigned short* B = wdT + (long)n0 * K_TOT + (long)e * I_DIM;
  const int nk = (e == 32) ? 32 : 16;   // K-steps of 64

  __shared__ unsigned short sA[128 * 64];
  __shared__ unsigned short sB[128 * 64];

  const int tid = threadIdx.x;
  const int lane = tid & 63;
  const int wid = tid >> 6;
  const int wm = wid >> 1, wn = wid & 1;
  const int l15 = lane & 15;
  const int lk  = (lane >> 4) * 8;
  const int srow = tid >> 3;                       // 0..31
  const int scol = (tid & 7) * 8;
  const int scolsw = (((tid & 7) ^ (srow & 7))) * 8;
  const int ksw = (l15 & 7) << 3;

  const f32x4 fz = {0.f, 0.f, 0.f, 0.f};
  f32x4 acc[4][4];
  #pragma unroll
  for (int i = 0; i < 4; ++i)
    #pragma unroll
    for (int j = 0; j < 4; ++j) acc[i][j] = fz;

  for (int t = 0; t < nk; ++t) {
    const int k0 = t * 64;
    const long koff = (long)(k0 & 1023) + (long)(k0 >> 10) * (2048L * 1024L);
    #pragma unroll
    for (int r = 0; r < 4; ++r)
      gld16(A + (long)(r * 32 + srow) * I_DIM + koff + scolsw,
            sA + (r * 32 + srow) * 64 + scol);
    #pragma unroll
    for (int r = 0; r < 4; ++r)
      gld16(B + (long)(r * 32 + srow) * K_TOT + k0 + scolsw,
            sB + (r * 32 + srow) * 64 + scol);
    __syncthreads();
    __builtin_amdgcn_s_setprio(1);
    #pragma unroll
    for (int kk = 0; kk < 2; ++kk) {
      const int ko = kk * 32 + lk;
      bf16x8 a[4], b[4];
      #pragma unroll
      for (int mi = 0; mi < 4; ++mi)
        a[mi] = *(const bf16x8*)(sA + (wm * 64 + mi * 16 + l15) * 64 + (ko ^ ksw));
      #pragma unroll
      for (int ni = 0; ni < 4; ++ni)
        b[ni] = *(const bf16x8*)(sB + (wn * 64 + ni * 16 + l15) * 64 + (ko ^ ksw));
      #pragma unroll
      for (int mi = 0; mi < 4; ++mi)
        #pragma unroll
        for (int ni = 0; ni < 4; ++ni)
          acc[mi][ni] = __builtin_amdgcn_mfma_f32_16x16x32_bf16(a[mi], b[ni], acc[mi][ni], 0, 0, 0);
    }
    __builtin_amdgcn_s_setprio(0);
    __syncthreads();
  }

  #pragma unroll
  for (int mi = 0; mi < 4; ++mi) {
    #pragma unroll
    for (int r = 0; r < 4; ++r) {
      const int slot = m0 + wm * 64 + mi * 16 + (lane >> 4) * 4 + r;
      if (slot < cnte) {
        unsigned short* pr = po + (long)(be + slot) * H_DIM + n0 + wn * 64;
        #pragma unroll
        for (int ni = 0; ni < 4; ++ni)
          pr[ni * 16 + l15] = f2bf(acc[mi][ni][r]);
      }
    }
  }
}

// ---------------------------------------------------------------------------
// Combine: out[t][h] = sum of the token's 8 routed partial rows + shared row.
// One block per token; 256 thr x 8 cols; bf16 -> fp32 sum -> fp32 store.
// ---------------------------------------------------------------------------
__global__ __launch_bounds__(256) void combine_kernel(
    const unsigned short* __restrict__ po,
    const int* __restrict__ base,
    const unsigned int* __restrict__ tslot,
    float* __restrict__ out)
{
  const int t = blockIdx.x;
  __shared__ int rows[9];
  if (threadIdx.x < 8) {
    const unsigned int pr = tslot[t * 8 + threadIdx.x];
    rows[threadIdx.x] = base[pr >> 16] + (int)(pr & 0xFFFFu);
  }
  if (threadIdx.x == 8) rows[8] = base[32] + t;
  __syncthreads();
  const int col = threadIdx.x * 8;
  float s[8];
  #pragma unroll
  for (int j = 0; j < 8; ++j) s[j] = 0.f;
  #pragma unroll
  for (int k = 0; k < 9; ++k) {
    const ushort4* p = (const ushort4*)(po + (long)rows[k] * H_DIM + col);
    const ushort4 v0 = p[0], v1 = p[1];
    s[0] += __uint_as_float((unsigned int)v0.x << 16);
    s[1] += __uint_as_float((unsigned int)v0.y << 16);
    s[2] += __uint_as_float((unsigned int)v0.z << 16);
    s[3] += __uint_as_float((unsigned int)v0.w << 16);
    s[4] += __uint_as_float((unsigned int)v1.x << 16);
    s[5] += __uint_as_float((unsigned int)v1.y << 16);
    s[6] += __uint_as_float((unsigned int)v1.z << 16);
    s[7] += __uint_as_float((unsigned int)v1.w << 16);
  }
  float4 o0 = {s[0], s[1], s[2], s[3]};
  float4 o1 = {s[4], s[5], s[6], s[7]};
  *(float4*)(out + (long)t * H_DIM + col) = o0;
  *(float4*)(out + (long)t * H_DIM + col + 4) = o1;
}

// ---------------------------------------------------------------------------
extern "C" void kernel_launch(void* const* d_in, const int* in_sizes, int n_in,
                              void* d_out, int out_size, void* d_ws, size_t ws_size,
                              hipStream_t stream) {
  (void)in_sizes; (void)n_in; (void)out_size; (void)ws_size;
  const float* x   = (const float*)d_in[0];
  const float* gw  = (const float*)d_in[1];
  const float* wg  = (const float*)d_in[2];
  const float* wu  = (const float*)d_in[3];
  const float* wd  = (const float*)d_in[4];
  const float* wsg = (const float*)d_in[5];
  const float* wsu = (const float*)d_in[6];
  const float* wsd = (const float*)d_in[7];
  float* out = (float*)d_out;
  char* ws = (char*)d_ws;

  int*            cnt   = (int*)(ws + OFF_CNT);
  int*            ntgu  = (int*)(ws + OFF_NTGU);
  int*            ntdn  = (int*)(ws + OFF_NTDN);
  int*            basep = (int*)(ws + OFF_BASE);
  unsigned int*   tgu   = (unsigned int*)(ws + OFF_TGU);
  unsigned int*   tdn   = (unsigned int*)(ws + OFF_TDN);
  unsigned int*   pairs = (unsigned int*)(ws + OFF_PAIRS);
  unsigned int*   tslot = (unsigned int*)(ws + OFF_TSLOT);
  unsigned short* xb    = (unsigned short*)(ws + OFF_XB);
  unsigned short* wgT   = (unsigned short*)(ws + OFF_WGT);
  unsigned short* wuT   = (unsigned short*)(ws + OFF_WUT);
  unsigned short* wsgT  = (unsigned short*)(ws + OFF_WSGT);
  unsigned short* wsuT  = (unsigned short*)(ws + OFF_WSUT);
  unsigned short* wdT   = (unsigned short*)(ws + OFF_WDT);
  unsigned short* actb  = (unsigned short*)(ws + OFF_ACT);
  unsigned short* pob   = (unsigned short*)(ws + OFF_PO);   // aliases wgT

  hipMemsetAsync(ws + OFF_CNT, 0, 256, stream);           // cnt + nt

  // router (emits pair lists, tslot, and xb via fused cvt)
  router_kernel<<<T_TOK, 256, 0, stream>>>(x, gw, cnt, pairs, tslot, xb);
  build_tiles_kernel<<<1, 256, 0, stream>>>(cnt, basep, tgu, ntgu, tdn, ntdn,
                                            pairs);

  // transpose A: gate/up weights (wg, wu, wsg, wsu)
  TDescTable ta;
  ta.in[0] = wg;  ta.out[0] = wgT;  ta.C[0] = I_DIM;  ta.ldout[0] = H_DIM;
  ta.in_bs[0] = (long)H_DIM * I_DIM; ta.out_bs[0] = (long)I_DIM * H_DIM;
  ta.nbx[0] = I_DIM / 64; ta.nbxy[0] = (I_DIM / 64) * (H_DIM / 256);
  ta.in[1] = wu;  ta.out[1] = wuT;  ta.C[1] = I_DIM;  ta.ldout[1] = H_DIM;
  ta.in_bs[1] = (long)H_DIM * I_DIM; ta.out_bs[1] = (long)I_DIM * H_DIM;
  ta.nbx[1] = I_DIM / 64; ta.nbxy[1] = (I_DIM / 64) * (H_DIM / 256);
  ta.in[2] = wsg; ta.out[2] = wsgT; ta.C[2] = IS_DIM; ta.ldout[2] = H_DIM;
  ta.in_bs[2] = 0; ta.out_bs[2] = 0;
  ta.nbx[2] = IS_DIM / 64; ta.nbxy[2] = (IS_DIM / 64) * (H_DIM / 256);
  ta.in[3] = wsu; ta.out[3] = wsuT; ta.C[3] = IS_DIM; ta.ldout[3] = H_DIM;
  ta.in_bs[3] = 0; ta.out_bs[3] = 0;
  ta.nbx[3] = IS_DIM / 64; ta.nbxy[3] = (IS_DIM / 64) * (H_DIM / 256);
  for (int i = 4; i < 6; ++i) {
    ta.in[i] = ta.in[3]; ta.out[i] = ta.out[3]; ta.C[i] = ta.C[3];
    ta.ldout[i] = ta.ldout[3]; ta.in_bs[i] = 0; ta.out_bs[i] = 0;
    ta.nbx[i] = 1; ta.nbxy[i] = 1;
  }
  ta.start[0] = 0;
  ta.start[1] = ta.start[0] + ta.nbxy[0] * E_NUM;
  ta.start[2] = ta.start[1] + ta.nbxy[1] * E_NUM;
  ta.start[3] = ta.start[2] + ta.nbxy[2];
  ta.start[4] = ta.start[3] + ta.nbxy[3];
  ta.start[5] = ta.start[4];
  ta.start[6] = ta.start[4];
  transpose_fused<<<ta.start[4], 256, 0, stream>>>(ta);

  // unified gate+up (routed + shared pseudo-experts) -> compact act
  gate_up_moe_kernel<<<dim3(16, GU_TILES), 256, 0, stream>>>(
      xb, wgT, wuT, wsgT, wsuT, cnt, basep, pairs, tgu, ntgu, actb);

  // transpose B: down weights (wd, wsd) — wgT region now dead, po aliases it
  TDescTable tb;
  tb.in[0] = wd;  tb.out[0] = wdT;  tb.C[0] = H_DIM;  tb.ldout[0] = K_TOT;
  tb.in_bs[0] = (long)I_DIM * H_DIM; tb.out_bs[0] = (long)I_DIM;
  tb.nbx[0] = H_DIM / 64; tb.nbxy[0] = (H_DIM / 64) * (I_DIM / 256);
  tb.in[1] = wsd; tb.out[1] = wdT + E_NUM * I_DIM; tb.C[1] = H_DIM;
  tb.ldout[1] = K_TOT; tb.in_bs[1] = 0; tb.out_bs[1] = 0;
  tb.nbx[1] = H_DIM / 64; tb.nbxy[1] = (H_DIM / 64) * (IS_DIM / 256);
  for (int i = 2; i < 6; ++i) {
    tb.in[i] = tb.in[1]; tb.out[i] = tb.out[1]; tb.C[i] = tb.C[1];
    tb.ldout[i] = tb.ldout[1]; tb.in_bs[i] = 0; tb.out_bs[i] = 0;
    tb.nbx[i] = 1; tb.nbxy[i] = 1;
  }
  tb.start[0] = 0;
  tb.start[1] = tb.start[0] + tb.nbxy[0] * E_NUM;
  tb.start[2] = tb.start[1] + tb.nbxy[1];
  tb.start[3] = tb.start[2];
  tb.start[4] = tb.start[2];
  tb.start[5] = tb.start[2];
  tb.start[6] = tb.start[2];
  transpose_fused<<<tb.start[2], 256, 0, stream>>>(tb);

  // unified down (routed K=1024, shared K=2048) -> plain-store partials
  down_moe_kernel<<<dim3(16, DN_TILES), 256, 0, stream>>>(
      actb, wdT, cnt, basep, tdn, ntdn, pob);

  // gather-combine: 9 partial rows per token -> out
  combine_kernel<<<T_TOK, 256, 0, stream>>>(pob, basep, tslot, out);
}